// Round 19
// baseline (173.249 us; speedup 1.0000x reference)
//
#include <hip/hip_runtime.h>
#include <math.h>

#define LMAXP1 33
#define EDIM   256
#define FBIG   3.0e38f

typedef _Float16 half8 __attribute__((ext_vector_type(8)));
typedef float    f32x4 __attribute__((ext_vector_type(4)));

__device__ inline unsigned pk2h(_Float16 a, _Float16 b) {
    union { _Float16 h[2]; unsigned u; } q; q.h[0] = a; q.h[1] = b; return q.u;
}

// ---------------------------------------------------------------------------
// Convert fp32 matrix -> fp16 hi/lo planes with scale.
// ---------------------------------------------------------------------------
__global__ __launch_bounds__(256)
void k_convw(const float* __restrict__ W, unsigned* __restrict__ Wh,
             unsigned* __restrict__ Wl, int npairs, float scale) {
    const int stride = gridDim.x * blockDim.x;
    for (int i = blockIdx.x * blockDim.x + threadIdx.x; i < npairs; i += stride) {
        const float a0 = W[2*i] * scale, a1 = W[2*i+1] * scale;
        const _Float16 h0 = (_Float16)a0, h1 = (_Float16)a1;
        const _Float16 l0 = (_Float16)(a0 - (float)h0);
        const _Float16 l1 = (_Float16)(a1 - (float)h1);
        Wh[i] = pk2h(h0, h1); Wl[i] = pk2h(l0, l1);
    }
}

// ---------------------------------------------------------------------------
// Row norms from fp16 planes: Norms[row] = sum((hi+lo)^2). 1 wave per row.
// ---------------------------------------------------------------------------
__global__ __launch_bounds__(256)
void k_norms(const unsigned* __restrict__ Eh, const unsigned* __restrict__ El,
             float* __restrict__ Norms, int Mtot) {
    const int row  = blockIdx.x * 4 + (threadIdx.x >> 6);
    const int lane = threadIdx.x & 63;
    if (row >= Mtot) return;
    const uint2 h2 = *(const uint2*)(Eh + (size_t)row * 128 + lane * 2);
    const uint2 l2 = *(const uint2*)(El + (size_t)row * 128 + lane * 2);
    union { unsigned u; _Float16 h[2]; } qh, ql;
    float s = 0.f;
    qh.u = h2.x; ql.u = l2.x;
    { const float x0 = (float)qh.h[0] + (float)ql.h[0];
      const float x1 = (float)qh.h[1] + (float)ql.h[1];
      s = fmaf(x0, x0, s); s = fmaf(x1, x1, s); }
    qh.u = h2.y; ql.u = l2.y;
    { const float x0 = (float)qh.h[0] + (float)ql.h[0];
      const float x1 = (float)qh.h[1] + (float)ql.h[1];
      s = fmaf(x0, x0, s); s = fmaf(x1, x1, s); }
    #pragma unroll
    for (int off = 32; off > 0; off >>= 1) s += __shfl_xor(s, off);
    if (lane == 0) Norms[row] = s;
}

// ---------------------------------------------------------------------------
// Split-K GEMM (NT) via fp16-split MFMA, v3:
//  * B fragments loaded DIRECTLY from global (planes are L2-resident, 2 MB)
//    -> no B LDS staging, no B bank conflicts.
//  * A double-buffered in LDS, ONE barrier per K-step; next-A global loads
//    issued before MFMA, conversion after (hidden under MFMA).
// BM=64 x BN=128 (grid.y = 2). LDS 20.5 KB.
// ---------------------------------------------------------------------------
#define ASTR 20   // uints per LDS k-row (80B)
__global__ __launch_bounds__(256)
void k_gemm_splitk(const float* __restrict__ S0, int n0,
                   const float* __restrict__ S1, int n1,
                   const float* __restrict__ S2,
                   const unsigned* __restrict__ Wh, const unsigned* __restrict__ Wl,
                   float* __restrict__ Part, int Mtot, int K, int kchunk) {
    __shared__ alignas(16) unsigned AsH[2][64 * ASTR], AsL[2][64 * ASTR];
    const int tid = threadIdx.x;
    const int m0  = blockIdx.x * 64;
    const int nc0 = blockIdx.y * 128;
    const int ks  = blockIdx.z;
    const int kb  = ks * kchunk;
    const int ke  = (kb + kchunk < K) ? kb + kchunk : K;

    const int sar = tid >> 2, sak = (tid & 3) << 3;
    const int gr  = m0 + sar;
    const float* srow = nullptr;
    if (gr < n0)            srow = S0 + (size_t)gr * K;
    else if (gr < n0 + n1)  srow = S1 + (size_t)(gr - n0) * K;
    else if (gr < Mtot)     srow = S2;

    const int lane = tid & 63, wv = tid >> 6;
    const int wc = wv << 5;                     // wave col base (0,32,64,96)
    const int lr = lane & 15, lq = lane >> 4;

    // per-lane B row base (uints); ct adds 16 rows, k0 adds (k0>>1)+lq*4
    const size_t browu = (size_t)(nc0 + wc + lr) * (size_t)(K >> 1);
    const size_t bct   = (size_t)16 * (size_t)(K >> 1);

    f32x4 acc[4][2] = {};

    float xa[8];
    #pragma unroll
    for (int j = 0; j < 8; ++j) xa[j] = 0.f;
    if (srow) {
        const float4 f0 = *(const float4*)(srow + kb + sak + 0);
        const float4 f1 = *(const float4*)(srow + kb + sak + 4);
        xa[0]=f0.x; xa[1]=f0.y; xa[2]=f0.z; xa[3]=f0.w;
        xa[4]=f1.x; xa[5]=f1.y; xa[6]=f1.z; xa[7]=f1.w;
    }
    {   // prologue: convert + store buf 0
        unsigned uh[4], ul[4];
        #pragma unroll
        for (int j = 0; j < 4; ++j) {
            const _Float16 h0 = (_Float16)xa[2*j],   h1 = (_Float16)xa[2*j+1];
            const _Float16 l0 = (_Float16)(xa[2*j]   - (float)h0);
            const _Float16 l1 = (_Float16)(xa[2*j+1] - (float)h1);
            uh[j] = pk2h(h0, h1); ul[j] = pk2h(l0, l1);
        }
        *(uint4*)(AsH[0] + sar * ASTR + (sak >> 1)) = make_uint4(uh[0],uh[1],uh[2],uh[3]);
        *(uint4*)(AsL[0] + sar * ASTR + (sak >> 1)) = make_uint4(ul[0],ul[1],ul[2],ul[3]);
    }
    __syncthreads();

    int buf = 0;
    for (int k0 = kb; k0 < ke; k0 += 32, buf ^= 1) {
        const bool hasNext = (k0 + 32 < ke);
        // issue next-A global loads early (latency hidden under MFMA below)
        if (hasNext && srow) {
            const float4 f0 = *(const float4*)(srow + k0 + 32 + sak + 0);
            const float4 f1 = *(const float4*)(srow + k0 + 32 + sak + 4);
            xa[0]=f0.x; xa[1]=f0.y; xa[2]=f0.z; xa[3]=f0.w;
            xa[4]=f1.x; xa[5]=f1.y; xa[6]=f1.z; xa[7]=f1.w;
        }
        // B fragments directly from global (L2-resident planes)
        const size_t bko = (size_t)(k0 >> 1) + (size_t)(lq << 2);
        half8 bhv[2], blv[2];
        #pragma unroll
        for (int ct = 0; ct < 2; ++ct) {
            bhv[ct] = *(const half8*)(Wh + browu + (size_t)ct * bct + bko);
            blv[ct] = *(const half8*)(Wl + browu + (size_t)ct * bct + bko);
        }
        // MFMA from As[buf]
        #pragma unroll
        for (int rt = 0; rt < 4; ++rt) {
            const int ar = rt * 16 + lr;
            const half8 ah = *(const half8*)((const char*)AsH[buf] + ar * 80 + lq * 16);
            const half8 al = *(const half8*)((const char*)AsL[buf] + ar * 80 + lq * 16);
            #pragma unroll
            for (int ct = 0; ct < 2; ++ct) {
                acc[rt][ct] = __builtin_amdgcn_mfma_f32_16x16x32_f16(ah, bhv[ct], acc[rt][ct], 0, 0, 0);
                acc[rt][ct] = __builtin_amdgcn_mfma_f32_16x16x32_f16(ah, blv[ct], acc[rt][ct], 0, 0, 0);
                acc[rt][ct] = __builtin_amdgcn_mfma_f32_16x16x32_f16(al, bhv[ct], acc[rt][ct], 0, 0, 0);
            }
        }
        // convert + store next A into the other buffer (after MFMA issues)
        if (hasNext) {
            unsigned uh[4], ul[4];
            #pragma unroll
            for (int j = 0; j < 4; ++j) {
                const _Float16 h0 = (_Float16)xa[2*j],   h1 = (_Float16)xa[2*j+1];
                const _Float16 l0 = (_Float16)(xa[2*j]   - (float)h0);
                const _Float16 l1 = (_Float16)(xa[2*j+1] - (float)h1);
                uh[j] = pk2h(h0, h1); ul[j] = pk2h(l0, l1);
            }
            *(uint4*)(AsH[buf ^ 1] + sar * ASTR + (sak >> 1)) = make_uint4(uh[0],uh[1],uh[2],uh[3]);
            *(uint4*)(AsL[buf ^ 1] + sar * ASTR + (sak >> 1)) = make_uint4(ul[0],ul[1],ul[2],ul[3]);
        }
        __syncthreads();
    }

    float* pout = Part + (size_t)ks * ((size_t)Mtot * EDIM);
    const float sc = 1.0f / 1024.0f;
    #pragma unroll
    for (int rt = 0; rt < 4; ++rt) {
        #pragma unroll
        for (int r = 0; r < 4; ++r) {
            const int grr = m0 + rt * 16 + lq * 4 + r;
            if (grr >= Mtot) continue;
            #pragma unroll
            for (int ct = 0; ct < 2; ++ct)
                pout[(size_t)grr * EDIM + nc0 + wc + ct * 16 + lr] = acc[rt][ct][r] * sc;
        }
    }
}

// ---------------------------------------------------------------------------
// Reduce split-K partials + bias + relu -> fp16 hi/lo planes of H.
// ---------------------------------------------------------------------------
__global__ __launch_bounds__(256)
void k_reduce_bias_relu(const float* __restrict__ Part,
                        const float* __restrict__ bias,
                        unsigned* __restrict__ Hh, unsigned* __restrict__ Hl,
                        int S, size_t MN4) {
    const size_t i = (size_t)blockIdx.x * blockDim.x + threadIdx.x;
    const size_t stride = (size_t)gridDim.x * blockDim.x;
    const size_t MN = MN4 * 4;
    for (size_t i4 = i; i4 < MN4; i4 += stride) {
        float4 s = ((const float4*)Part)[i4];
        for (int z = 1; z < S; ++z)
            { const float4 q = ((const float4*)(Part + (size_t)z * MN))[i4];
              s.x += q.x; s.y += q.y; s.z += q.z; s.w += q.w; }
        const float4 b = ((const float4*)bias)[i4 & 63];
        s.x = fmaxf(s.x + b.x, 0.f); s.y = fmaxf(s.y + b.y, 0.f);
        s.z = fmaxf(s.z + b.z, 0.f); s.w = fmaxf(s.w + b.w, 0.f);
        const _Float16 hx = (_Float16)s.x, hy = (_Float16)s.y;
        const _Float16 hz = (_Float16)s.z, hw = (_Float16)s.w;
        Hh[i4*2+0] = pk2h(hx, hy);
        Hh[i4*2+1] = pk2h(hz, hw);
        Hl[i4*2+0] = pk2h((_Float16)(s.x - (float)hx), (_Float16)(s.y - (float)hy));
        Hl[i4*2+1] = pk2h((_Float16)(s.z - (float)hz), (_Float16)(s.w - (float)hw));
    }
}

// ---------------------------------------------------------------------------
// Pure-fp16 GEMM (planes in), fused bias+relu, emits Emb as fp16 hi/lo planes.
// BM=64 x BN=256 (K=256, one shot).
// ---------------------------------------------------------------------------
__global__ __launch_bounds__(256)
void k_gemm_f16(const unsigned* __restrict__ Ah, const unsigned* __restrict__ Al,
                const unsigned* __restrict__ Wh, const unsigned* __restrict__ Wl,
                const float* __restrict__ bias,
                unsigned* __restrict__ Eh, unsigned* __restrict__ El,
                int Mtot, int K) {
    __shared__ alignas(16) unsigned AsH[64 * ASTR],  AsL[64 * ASTR];
    __shared__ alignas(16) unsigned BsH[256 * ASTR], BsL[256 * ASTR];
    const int tid = threadIdx.x;
    const int m0  = blockIdx.x * 64;

    const int sar = tid >> 2, sak = (tid & 3) << 3;
    const int gr  = m0 + sar;
    const bool arow = (gr < Mtot);

    const int lane = tid & 63, wv = tid >> 6;
    const int wc = wv << 6;
    const int lr = lane & 15, lq = lane >> 4;

    f32x4 acc[4][4] = {};

    for (int k0 = 0; k0 < K; k0 += 32) {
        {
            uint4 vh = make_uint4(0,0,0,0), vl = vh;
            if (arow) {
                const size_t uoff = (size_t)gr * (K >> 1) + ((k0 + sak) >> 1);
                vh = *(const uint4*)(Ah + uoff);
                vl = *(const uint4*)(Al + uoff);
            }
            *(uint4*)(AsH + sar * ASTR + (sak >> 1)) = vh;
            *(uint4*)(AsL + sar * ASTR + (sak >> 1)) = vl;
        }
        #pragma unroll
        for (int it = 0; it < 4; ++it) {
            const int idx = tid + it * 256;
            const int br = idx >> 2, bk = (idx & 3) << 3;
            const size_t uoff = (size_t)br * (K >> 1) + ((k0 + bk) >> 1);
            *(uint4*)(BsH + br * ASTR + (bk >> 1)) = *(const uint4*)(Wh + uoff);
            *(uint4*)(BsL + br * ASTR + (bk >> 1)) = *(const uint4*)(Wl + uoff);
        }
        __syncthreads();

        half8 bhv[4], blv[4];
        #pragma unroll
        for (int ct = 0; ct < 4; ++ct) {
            const int br = wc + ct * 16 + lr;
            bhv[ct] = *(const half8*)((const char*)BsH + br * 80 + lq * 16);
            blv[ct] = *(const half8*)((const char*)BsL + br * 80 + lq * 16);
        }
        #pragma unroll
        for (int rt = 0; rt < 4; ++rt) {
            const int ar = rt * 16 + lr;
            const half8 ah = *(const half8*)((const char*)AsH + ar * 80 + lq * 16);
            const half8 al = *(const half8*)((const char*)AsL + ar * 80 + lq * 16);
            #pragma unroll
            for (int ct = 0; ct < 4; ++ct) {
                acc[rt][ct] = __builtin_amdgcn_mfma_f32_16x16x32_f16(ah, bhv[ct], acc[rt][ct], 0, 0, 0);
                acc[rt][ct] = __builtin_amdgcn_mfma_f32_16x16x32_f16(ah, blv[ct], acc[rt][ct], 0, 0, 0);
                acc[rt][ct] = __builtin_amdgcn_mfma_f32_16x16x32_f16(al, bhv[ct], acc[rt][ct], 0, 0, 0);
            }
        }
        __syncthreads();
    }

    _Float16* ph = (_Float16*)Eh;
    _Float16* pl = (_Float16*)El;
    const float sc = 1.0f / 1024.0f;
    #pragma unroll
    for (int rt = 0; rt < 4; ++rt) {
        #pragma unroll
        for (int r = 0; r < 4; ++r) {
            const int grr = m0 + rt * 16 + lq * 4 + r;
            if (grr >= Mtot) continue;
            #pragma unroll
            for (int ct = 0; ct < 4; ++ct) {
                const int gc = wc + ct * 16 + lr;
                const float vv = fmaxf(acc[rt][ct][r] * sc + bias[gc], 0.0f);
                const _Float16 hv = (_Float16)vv;
                ph[(size_t)grr * EDIM + gc] = hv;
                pl[(size_t)grr * EDIM + gc] = (_Float16)(vv - (float)hv);
            }
        }
    }
}

// ---------------------------------------------------------------------------
// Direct fp32 GEMM (NT, fused bias+relu) — fallback only (ws too small).
// ---------------------------------------------------------------------------
__global__ __launch_bounds__(256)
void k_embed_gemm(const float* __restrict__ S0, int n0,
                  const float* __restrict__ S1, int n1,
                  const float* __restrict__ S2,
                  const float* __restrict__ W, const float* __restrict__ bias,
                  float* __restrict__ C, int Mtot, int K) {
    __shared__ alignas(16) float As[16][68];
    __shared__ alignas(16) float Bs[16][68];
    const int tid  = threadIdx.x;
    const int tx   = tid & 15, ty = tid >> 4;
    const int m0   = blockIdx.x * 64, nc0 = blockIdx.y * 64;
    const int lrow = tid >> 2;
    const int lk4  = (tid & 3) << 2;

    const int gr = m0 + lrow;
    const float* srow = nullptr;
    if (gr < n0)            srow = S0 + (size_t)gr * K;
    else if (gr < n0 + n1)  srow = S1 + (size_t)(gr - n0) * K;
    else if (gr < Mtot)     srow = S2;
    const float* wrow = W + (size_t)(nc0 + lrow) * K;

    float acc[4][4] = {};
    for (int k0 = 0; k0 < K; k0 += 16) {
        float4 va = make_float4(0.f, 0.f, 0.f, 0.f);
        if (srow) va = *(const float4*)(srow + k0 + lk4);
        const float4 vb = *(const float4*)(wrow + k0 + lk4);
        As[lk4+0][lrow] = va.x; As[lk4+1][lrow] = va.y;
        As[lk4+2][lrow] = va.z; As[lk4+3][lrow] = va.w;
        Bs[lk4+0][lrow] = vb.x; Bs[lk4+1][lrow] = vb.y;
        Bs[lk4+2][lrow] = vb.z; Bs[lk4+3][lrow] = vb.w;
        __syncthreads();
        #pragma unroll
        for (int kk = 0; kk < 16; ++kk) {
            const float4 a4 = *(const float4*)&As[kk][ty << 2];
            const float4 b4 = *(const float4*)&Bs[kk][tx << 2];
            const float av[4] = {a4.x, a4.y, a4.z, a4.w};
            const float bv[4] = {b4.x, b4.y, b4.z, b4.w};
            #pragma unroll
            for (int i2 = 0; i2 < 4; ++i2)
                #pragma unroll
                for (int j2 = 0; j2 < 4; ++j2)
                    acc[i2][j2] = fmaf(av[i2], bv[j2], acc[i2][j2]);
        }
        __syncthreads();
    }
    #pragma unroll
    for (int i2 = 0; i2 < 4; ++i2) {
        const int grr = m0 + (ty << 2) + i2;
        if (grr >= Mtot) continue;
        #pragma unroll
        for (int j2 = 0; j2 < 4; ++j2) {
            const int gc = nc0 + (tx << 2) + j2;
            const float vv = acc[i2][j2] + bias[gc];
            C[(size_t)grr * EDIM + gc] = fmaxf(vv, 0.0f);
        }
    }
}

// ---------------------------------------------------------------------------
// Per-pair scaled edit-cost matrix via MFMA Gram; staging = plane copies,
// norms precomputed.
// ---------------------------------------------------------------------------
#define CSTR 36
__global__ __launch_bounds__(256)
void k_costs(const unsigned* __restrict__ Eh, const unsigned* __restrict__ El,
             const float* __restrict__ Norms,
             const int* __restrict__ len_s, const int* __restrict__ len_t,
             int Ns, int Nt, float* __restrict__ costs) {
    __shared__ alignas(16) unsigned Ah[34 * CSTR], Al[34 * CSTR];
    __shared__ alignas(16) unsigned Bh[34 * CSTR], Bl[34 * CSTR];
    __shared__ float dtile[LMAXP1 * LMAXP1];
    __shared__ float na[LMAXP1], nb[LMAXP1];
    __shared__ float red[256];
    __shared__ float s_scale;
    const int p = blockIdx.x, tid = threadIdx.x;
    const int n = len_s[p], m = len_t[p];
    int offs = 0, offt = 0;
    for (int j = 0; j < p; ++j) { offs += len_s[j]; offt += len_t[j]; }  // uniform
    const int veRow = Ns + Nt;
    const int tbase = Ns + offt;

    const int lane = tid & 63, wv = tid >> 6;
    const int lr = lane & 15, lq = lane >> 4;

    if (tid <= n)                       na[tid] = Norms[(tid < n) ? offs + tid : veRow];
    else if (tid >= 64 && tid - 64 <= m) nb[tid - 64] = Norms[(tid - 64 < m) ? tbase + tid - 64 : veRow];

    f32x4 g0 = {}, g1 = {}, g2 = {};
    const int t0 = wv, t1 = wv + 4, t2 = wv + 8;

    for (int k0 = 0; k0 < EDIM; k0 += 64) {
        for (int idx = tid; idx < 34 * 16; idx += 256) {
            const int r = idx >> 4, c4 = idx & 15;
            const int rowA = (r < n) ? offs + r : ((r == n) ? veRow : -1);
            const int rowB = (r < m) ? tbase + r : ((r == m) ? veRow : -1);
            uint2 vah = make_uint2(0,0), val = vah, vbh = vah, vbl = vah;
            if (rowA >= 0) {
                const size_t uo_ = (size_t)rowA * 128 + (k0 >> 1) + c4 * 2;
                vah = *(const uint2*)(Eh + uo_); val = *(const uint2*)(El + uo_);
            }
            if (rowB >= 0) {
                const size_t uo_ = (size_t)rowB * 128 + (k0 >> 1) + c4 * 2;
                vbh = *(const uint2*)(Eh + uo_); vbl = *(const uint2*)(El + uo_);
            }
            const int uo = r * CSTR + c4 * 2;
            *(uint2*)(Ah + uo) = vah; *(uint2*)(Al + uo) = val;
            *(uint2*)(Bh + uo) = vbh; *(uint2*)(Bl + uo) = vbl;
        }
        __syncthreads();

        #pragma unroll
        for (int kf = 0; kf < 2; ++kf) {
#define GRAM_TILE(T, G) { \
            const int tr_ = (T) / 3, tc_ = (T) % 3;                              \
            const int ar_ = tr_ * 16 + lr, br_ = tc_ * 16 + lr;                  \
            const half8 ah = *(const half8*)((const char*)Ah + ar_*144 + kf*64 + lq*16); \
            const half8 al = *(const half8*)((const char*)Al + ar_*144 + kf*64 + lq*16); \
            const half8 bh = *(const half8*)((const char*)Bh + br_*144 + kf*64 + lq*16); \
            const half8 bl = *(const half8*)((const char*)Bl + br_*144 + kf*64 + lq*16); \
            G = __builtin_amdgcn_mfma_f32_16x16x32_f16(ah, bh, G, 0, 0, 0);      \
            G = __builtin_amdgcn_mfma_f32_16x16x32_f16(ah, bl, G, 0, 0, 0);      \
            G = __builtin_amdgcn_mfma_f32_16x16x32_f16(al, bh, G, 0, 0, 0); }
            GRAM_TILE(t0, g0)
            GRAM_TILE(t1, g1)
            if (wv == 0) GRAM_TILE(t2, g2)
#undef GRAM_TILE
        }
        __syncthreads();
    }

#define DTILE_OUT(T, G) { \
    const int tr_ = (T) / 3, tc_ = (T) % 3;                                      \
    _Pragma("unroll")                                                            \
    for (int r = 0; r < 4; ++r) {                                                \
        const int i_ = tr_ * 16 + lq * 4 + r, j_ = tc_ * 16 + lr;                \
        if (i_ <= n && j_ <= m) {                                                \
            const float sq = fmaxf(na[i_] + nb[j_] - 2.0f * G[r], 0.0f);         \
            dtile[i_ * LMAXP1 + j_] = (sq > 0.0f) ? sqrtf(sq) : 0.0f;            \
        } } }
    DTILE_OUT(t0, g0)
    DTILE_OUT(t1, g1)
    if (wv == 0) DTILE_OUT(t2, g2)
#undef DTILE_OUT
    __syncthreads();

    float lsum = 0.f;
    const int m1 = m + 1;
    const int cells = (n + 1) * m1;
    for (int c = tid; c < cells; c += 256) {
        const int i = c / m1, j = c - i * m1;
        lsum += dtile[i * LMAXP1 + j];
    }
    red[tid] = lsum;
    __syncthreads();
    for (int s = 128; s > 0; s >>= 1) {
        if (tid < s) red[tid] += red[tid + s];
        __syncthreads();
    }
    if (tid == 0) s_scale = (float)(n * m) / red[0];
    __syncthreads();
    const float scale = s_scale;
    for (int idx = tid; idx < LMAXP1 * LMAXP1; idx += 256) {
        const int i = idx / LMAXP1, j = idx - i * LMAXP1;
        const float v = (i <= n && j <= m) ? dtile[i * LMAXP1 + j] * scale : 0.0f;
        costs[(size_t)p * (LMAXP1 * LMAXP1) + idx] = v;
    }
}

// ---------------------------------------------------------------------------
// LAP: reduced max(n,m)^2 LAP; col-reduction/greedy + ARR + JV Dijkstra.
// (R17-verified exact: absmax 0.0)
// ---------------------------------------------------------------------------
__device__ inline int rdlane_i(int v, int l) { return __builtin_amdgcn_readlane(v, l); }
__device__ inline float rdlane_f(float v, int l) {
    return __int_as_float(__builtin_amdgcn_readlane(__float_as_int(v), l));
}
__device__ inline unsigned wave_umin64(unsigned x) {
#define DPPMINU(ctrl) { unsigned t_ = (unsigned)__builtin_amdgcn_update_dpp(  \
        (int)x, (int)x, (ctrl), 0xf, 0xf, false);                             \
        x = (t_ < x) ? t_ : x; }
    DPPMINU(0xB1)
    DPPMINU(0x4E)
    DPPMINU(0x141)
    DPPMINU(0x140)
    DPPMINU(0x142)
    DPPMINU(0x143)
#undef DPPMINU
    return (unsigned)__builtin_amdgcn_readlane((int)x, 63);
}

__global__ __launch_bounds__(64)
void k_lap(const float* __restrict__ costs, const int* __restrict__ len_s,
           const int* __restrict__ len_t, float* __restrict__ aligns,
           float* __restrict__ geds) {
    __shared__ float ec[LMAXP1 * LMAXP1];
    __shared__ float Ms[33 * 64];
    const int p = blockIdx.x, lane = threadIdx.x;
    const int n = len_s[p], m = len_t[p];
    const float* cp = costs + (size_t)p * (LMAXP1 * LMAXP1);
    for (int idx = lane; idx < LMAXP1 * LMAXP1; idx += 64) ec[idx] = cp[idx];
    __syncthreads();

    const bool swp = (n > m);
    const int R  = swp ? n : m;
    const int S_ = swp ? m : n;
    const bool vec = (lane >= 1 && lane <= R);

    for (int r = 1; r <= R; ++r) {
        float cv = FBIG;
        const int i0b = r - 1, j0b = lane - 1;
        if (vec) {
            if (!swp) {
                const float ins = ec[n * LMAXP1 + j0b];
                cv = (i0b < S_)
                   ? fminf(ec[i0b * LMAXP1 + j0b], ec[i0b * LMAXP1 + m] + ins)
                   : ins;
            } else {
                const float ins = ec[j0b * LMAXP1 + m];
                cv = (i0b < S_)
                   ? fminf(ec[j0b * LMAXP1 + i0b], ec[n * LMAXP1 + i0b] + ins)
                   : ins;
            }
        }
        Ms[(r << 6) + lane] = cv;
    }
    __syncthreads();

    // ---- column reduction + greedy ----
    float v_l = 0.0f;
    int amin_l = 0;
    if (vec) {
        float best = FBIG;
        for (int r = 1; r <= R; ++r) {
            const float c = Ms[(r << 6) + lane];
            if (c < best) { best = c; amin_l = r; }
        }
        v_l = best;
    }
    int p_l = 0;
    unsigned long long rowfree = ((1ull << R) - 1ull) << 1;
    for (int j = 1; j <= R; ++j) {
        const int ai = rdlane_i(amin_l, j);
        if ((rowfree >> ai) & 1ull) {
            if (lane == j) p_l = ai;
            rowfree &= ~(1ull << ai);
        }
    }

    // ---- augmenting row reduction (ARR) ----
    float ucol = 0.0f;
    {
        unsigned long long q = rowfree;
        int pops = 0;
        const int cap = 3 * R;
        while (q && pops < cap) {
            const int i = __ffsll(q) - 1;
            q &= ~(1ull << i);
            ++pops;
            const float rc = vec ? fmaxf(Ms[(i << 6) + lane] - v_l, 0.0f) : FBIG;
            const unsigned key = (__float_as_uint(rc) & ~63u) | (unsigned)lane;
            const unsigned k1 = wave_umin64(key);
            int j1 = (int)(k1 & 63u);
            const float min1 = rdlane_f(rc, j1);
            const unsigned key2 = (lane == j1) ? 0xFFFFFFFFu : key;
            const unsigned k2 = wave_umin64(key2);
            const float min2 = rdlane_f(rc, (int)(k2 & 63u));
            int owner = rdlane_i(p_l, j1);
            const bool strict = (min1 < min2);
            if (!strict) {
                const unsigned long long ball =
                    __ballot(vec && (rc == min1) && (p_l == 0));
                if (ball == 0ull) continue;
                j1 = __ffsll(ball) - 1;
                j1 = __builtin_amdgcn_readfirstlane(j1);
                owner = 0;
            }
            if (lane == j1) {
                p_l = i; ucol = min2;
                if (strict) v_l -= (min2 - min1);
            }
            rowfree &= ~(1ull << i);
            if (owner != 0) { rowfree |= (1ull << owner); q |= (1ull << owner); }
        }
    }

    // ---- JV Dijkstra for remaining free rows ----
    float minv_l = FBIG;
    int way_l = 0;

    for (int i = 1; i <= R; ++i) {
        if (!((rowfree >> i) & 1ull)) continue;
        if (lane == 0) { p_l = i; ucol = 0.0f; }
        minv_l = FBIG;
        int used_l = 0;
        int j0 = 0, i0 = i;
        float u_i0 = 0.0f;
        while (true) {
            if (lane == j0) used_l = 1;
            const float cur = Ms[(i0 << 6) + lane] - u_i0 - v_l;
            const bool unused = vec && !used_l;
            if (unused && cur < minv_l) { minv_l = cur; way_l = j0; }
            const float mval = unused ? fmaxf(minv_l, 0.0f) : FBIG;
            const unsigned key = (__float_as_uint(mval) & ~63u) | (unsigned)lane;
            const unsigned kmin = wave_umin64(key);
            const int j1 = (int)(kmin & 63u);
            const float delta = rdlane_f(minv_l, j1);
            if (used_l) { ucol += delta; v_l -= delta; }
            if (unused) minv_l -= delta;
            j0 = j1;
            i0 = rdlane_i(p_l, j1);
            u_i0 = rdlane_f(ucol, j1);
            if (i0 == 0) break;
        }
        int jj = j0;
        while (jj != 0) {
            const int   j1a = rdlane_i(way_l, jj);
            const int   pn  = rdlane_i(p_l, j1a);
            const float un  = rdlane_f(ucol, j1a);
            if (lane == jj) { p_l = pn; ucol = un; }
            jj = j1a;
        }
    }

    // ---- decode ----
    float* ap = aligns + (size_t)p * (LMAXP1 * LMAXP1);
    for (int idx = lane; idx < LMAXP1 * LMAXP1; idx += 64) ap[idx] = 0.0f;
    __syncthreads();
    float gedv = 0.0f;
    if (vec) {
        const int i0b = p_l - 1;
        const int j0b = lane - 1;
        if (!swp) {
            if (i0b < S_) {
                const float sub = ec[i0b * LMAXP1 + j0b];
                const float alt = ec[i0b * LMAXP1 + m] + ec[n * LMAXP1 + j0b];
                if (sub <= alt) { ap[i0b * LMAXP1 + j0b] = 1.0f; gedv = sub; }
                else { ap[i0b * LMAXP1 + m] = 1.0f;
                       ap[n * LMAXP1 + j0b] = 1.0f;
                       gedv = alt; }
            } else {
                ap[n * LMAXP1 + j0b] = 1.0f;
                gedv = ec[n * LMAXP1 + j0b];
            }
        } else {
            if (i0b < S_) {
                const float sub = ec[j0b * LMAXP1 + i0b];
                const float alt = ec[n * LMAXP1 + i0b] + ec[j0b * LMAXP1 + m];
                if (sub <= alt) { ap[j0b * LMAXP1 + i0b] = 1.0f; gedv = sub; }
                else { ap[n * LMAXP1 + i0b] = 1.0f;
                       ap[j0b * LMAXP1 + m] = 1.0f;
                       gedv = alt; }
            } else {
                ap[j0b * LMAXP1 + m] = 1.0f;
                gedv = ec[j0b * LMAXP1 + m];
            }
        }
    }
    #pragma unroll
    for (int off = 32; off > 0; off >>= 1) gedv += __shfl_xor(gedv, off);
    if (lane == 0) geds[p] = gedv / (float)(n + m);
}

// ---------------------------------------------------------------------------
extern "C" void kernel_launch(void* const* d_in, const int* in_sizes, int n_in,
                              void* d_out, int out_size, void* d_ws, size_t ws_size,
                              hipStream_t stream) {
    const float* x_s = (const float*)d_in[0];
    const float* x_t = (const float*)d_in[1];
    const float* W1  = (const float*)d_in[2];
    const float* b1  = (const float*)d_in[3];
    const float* W2  = (const float*)d_in[4];
    const float* b2  = (const float*)d_in[5];
    const float* ve  = (const float*)d_in[6];
    const int* len_s = (const int*)d_in[7];
    const int* len_t = (const int*)d_in[8];
    const int P    = in_sizes[7];
    const int Ns   = in_sizes[0] / 2048;
    const int Nt   = in_sizes[1] / 2048;
    const int Mtot = Ns + Nt + 1;
    const size_t MN  = (size_t)Mtot * EDIM;          // even

    float* out_aligns = (float*)d_out;
    float* out_costs  = out_aligns + (size_t)P * LMAXP1 * LMAXP1;
    float* out_geds   = out_costs  + (size_t)P * LMAXP1 * LMAXP1;

    const dim3 b256(256);
    const int gx64 = (Mtot + 63) / 64;
    const int gnorm = (Mtot + 3) / 4;

    const size_t fixed = MN + 10240 + 2 * 262144 + 2 * 32768;
    int S = 0;
    if (ws_size >= (4 * MN + fixed) * sizeof(float)) S = 4;
    else if (ws_size >= (2 * MN + fixed) * sizeof(float)) S = 2;

    if (S > 0) {
        float* Part = (float*)d_ws;
        unsigned* Eh  = (unsigned*)Part;              // MN/2 uints (alias)
        unsigned* El  = Eh + MN / 2;
        unsigned* Hh  = (unsigned*)(Part + (size_t)S * MN);
        unsigned* Hl  = Hh + MN / 2;
        float* Norms  = (float*)(Hl + MN / 2);
        unsigned* W1h = (unsigned*)(Norms + 10240);
        unsigned* W1l = W1h + 262144;
        unsigned* W2h = W1l + 262144;
        unsigned* W2l = W2h + 32768;

        k_convw<<<dim3(1024), b256, 0, stream>>>(W1, W1h, W1l, 262144, 1024.0f);
        k_convw<<<dim3(128),  b256, 0, stream>>>(W2, W2h, W2l, 32768, 1024.0f);

        k_gemm_splitk<<<dim3(gx64, 2, S), b256, 0, stream>>>(
            x_s, Ns, x_t, Nt, ve, W1h, W1l, Part, Mtot, 2048, 2048 / S);

        const size_t MN4 = MN / 4;
        const int rblocks = (int)((MN4 + 255) / 256) < 2048
                          ? (int)((MN4 + 255) / 256) : 2048;
        k_reduce_bias_relu<<<dim3(rblocks), b256, 0, stream>>>(Part, b1, Hh, Hl, S, MN4);

        k_gemm_f16<<<dim3(gx64), b256, 0, stream>>>(Hh, Hl, W2h, W2l, b2, Eh, El, Mtot, 256);
        k_norms<<<dim3(gnorm), b256, 0, stream>>>(Eh, El, Norms, Mtot);

        k_costs<<<dim3(P), b256, 0, stream>>>(Eh, El, Norms, len_s, len_t, Ns, Nt, out_costs);
        k_lap<<<dim3(P), dim3(64), 0, stream>>>(out_costs, len_s, len_t, out_aligns, out_geds);
    } else {
        float* H   = (float*)d_ws;
        float* Emb = H + MN;
        unsigned* Eh = (unsigned*)(Emb + MN);
        unsigned* El = Eh + MN / 2;
        float* Norms = (float*)(El + MN / 2);
        k_embed_gemm<<<dim3(gx64, 4), b256, 0, stream>>>(
            x_s, Ns, x_t, Nt, ve, W1, b1, H, Mtot, 2048);
        k_embed_gemm<<<dim3(gx64, 4), b256, 0, stream>>>(
            H, Mtot, nullptr, 0, nullptr, W2, b2, Emb, Mtot, 256);
        k_convw<<<dim3(1024), b256, 0, stream>>>(Emb, Eh, El, (int)(MN / 2), 1.0f);
        k_norms<<<dim3(gnorm), b256, 0, stream>>>(Eh, El, Norms, Mtot);
        k_costs<<<dim3(P), b256, 0, stream>>>(Eh, El, Norms, len_s, len_t, Ns, Nt, out_costs);
        k_lap<<<dim3(P), dim3(64), 0, stream>>>(out_costs, len_s, len_t, out_aligns, out_geds);
    }
}

// Round 20
// 164.805 us; speedup vs baseline: 1.0512x; 1.0512x over previous
//
#include <hip/hip_runtime.h>
#include <math.h>

#define LMAXP1 33
#define EDIM   256
#define FBIG   3.0e38f

typedef _Float16 half8 __attribute__((ext_vector_type(8)));
typedef float    f32x4 __attribute__((ext_vector_type(4)));

__device__ inline unsigned pk2h(_Float16 a, _Float16 b) {
    union { _Float16 h[2]; unsigned u; } q; q.h[0] = a; q.h[1] = b; return q.u;
}

// ---------------------------------------------------------------------------
// Convert fp32 matrix -> fp16 hi/lo planes with scale.
// ---------------------------------------------------------------------------
__global__ __launch_bounds__(256)
void k_convw(const float* __restrict__ W, unsigned* __restrict__ Wh,
             unsigned* __restrict__ Wl, int npairs, float scale) {
    const int stride = gridDim.x * blockDim.x;
    for (int i = blockIdx.x * blockDim.x + threadIdx.x; i < npairs; i += stride) {
        const float a0 = W[2*i] * scale, a1 = W[2*i+1] * scale;
        const _Float16 h0 = (_Float16)a0, h1 = (_Float16)a1;
        const _Float16 l0 = (_Float16)(a0 - (float)h0);
        const _Float16 l1 = (_Float16)(a1 - (float)h1);
        Wh[i] = pk2h(h0, h1); Wl[i] = pk2h(l0, l1);
    }
}

// ---------------------------------------------------------------------------
// Row norms from fp16 planes: Norms[row] = sum((hi+lo)^2). 1 wave per row.
// ---------------------------------------------------------------------------
__global__ __launch_bounds__(256)
void k_norms(const unsigned* __restrict__ Eh, const unsigned* __restrict__ El,
             float* __restrict__ Norms, int Mtot) {
    const int row  = blockIdx.x * 4 + (threadIdx.x >> 6);
    const int lane = threadIdx.x & 63;
    if (row >= Mtot) return;
    const uint2 h2 = *(const uint2*)(Eh + (size_t)row * 128 + lane * 2);
    const uint2 l2 = *(const uint2*)(El + (size_t)row * 128 + lane * 2);
    union { unsigned u; _Float16 h[2]; } qh, ql;
    float s = 0.f;
    qh.u = h2.x; ql.u = l2.x;
    { const float x0 = (float)qh.h[0] + (float)ql.h[0];
      const float x1 = (float)qh.h[1] + (float)ql.h[1];
      s = fmaf(x0, x0, s); s = fmaf(x1, x1, s); }
    qh.u = h2.y; ql.u = l2.y;
    { const float x0 = (float)qh.h[0] + (float)ql.h[0];
      const float x1 = (float)qh.h[1] + (float)ql.h[1];
      s = fmaf(x0, x0, s); s = fmaf(x1, x1, s); }
    #pragma unroll
    for (int off = 32; off > 0; off >>= 1) s += __shfl_xor(s, off);
    if (lane == 0) Norms[row] = s;
}

// ---------------------------------------------------------------------------
// Split-K GEMM (NT) via fp16-split MFMA, v4: BM=128 x BN=128 (B re-fetch
// traffic halved vs BM=64 -> off the L2-BW wall). 4 waves, each 64x64 out
// (A 8 + B 8 ds_reads per 48 MFMA). B in LDS (R18-proven staging), 2
// barriers/K-step. LDS 41 KB -> 3 blocks/CU.
// ---------------------------------------------------------------------------
#define ASTR 20   // uints per LDS k-row (80B)
__global__ __launch_bounds__(256)
void k_gemm_splitk(const float* __restrict__ S0, int n0,
                   const float* __restrict__ S1, int n1,
                   const float* __restrict__ S2,
                   const unsigned* __restrict__ Wh, const unsigned* __restrict__ Wl,
                   float* __restrict__ Part, int Mtot, int K, int kchunk) {
    __shared__ alignas(16) unsigned AsH[128 * ASTR], AsL[128 * ASTR];
    __shared__ alignas(16) unsigned BsH[128 * ASTR], BsL[128 * ASTR];
    const int tid = threadIdx.x;
    const int m0  = blockIdx.x * 128;
    const int nc0 = blockIdx.y * 128;
    const int ks  = blockIdx.z;
    const int kb  = ks * kchunk;
    const int ke  = (kb + kchunk < K) ? kb + kchunk : K;

    const int sar = tid >> 1;              // A row 0..127
    const int sak = (tid & 1) << 4;        // A k-offset 0/16
    const int gr  = m0 + sar;
    const float* srow = nullptr;
    if (gr < n0)            srow = S0 + (size_t)gr * K;
    else if (gr < n0 + n1)  srow = S1 + (size_t)(gr - n0) * K;
    else if (gr < Mtot)     srow = S2;

    const int lane = tid & 63, wv = tid >> 6;
    const int wr = (wv & 1) << 6;          // wave row base 0/64
    const int wc = (wv >> 1) << 6;         // wave col base 0/64
    const int lr = lane & 15, lq = lane >> 4;

    f32x4 acc[4][4] = {};

    for (int k0 = kb; k0 < ke; k0 += 32) {
        {   // ---- stage A (128x32 fp32 -> hi/lo fp16), 16 elems/thread ----
            float x[16];
            if (srow) {
                const float4 f0 = *(const float4*)(srow + k0 + sak + 0);
                const float4 f1 = *(const float4*)(srow + k0 + sak + 4);
                const float4 f2 = *(const float4*)(srow + k0 + sak + 8);
                const float4 f3 = *(const float4*)(srow + k0 + sak + 12);
                x[0]=f0.x; x[1]=f0.y; x[2]=f0.z; x[3]=f0.w;
                x[4]=f1.x; x[5]=f1.y; x[6]=f1.z; x[7]=f1.w;
                x[8]=f2.x; x[9]=f2.y; x[10]=f2.z; x[11]=f2.w;
                x[12]=f3.x; x[13]=f3.y; x[14]=f3.z; x[15]=f3.w;
            } else {
                #pragma unroll
                for (int j = 0; j < 16; ++j) x[j] = 0.f;
            }
            unsigned uh[8], ul[8];
            #pragma unroll
            for (int j = 0; j < 8; ++j) {
                const _Float16 h0 = (_Float16)x[2*j],   h1 = (_Float16)x[2*j+1];
                const _Float16 l0 = (_Float16)(x[2*j]   - (float)h0);
                const _Float16 l1 = (_Float16)(x[2*j+1] - (float)h1);
                uh[j] = pk2h(h0, h1); ul[j] = pk2h(l0, l1);
            }
            unsigned* ph = AsH + sar * ASTR + (sak >> 1);
            unsigned* pl = AsL + sar * ASTR + (sak >> 1);
            ((uint4*)ph)[0] = make_uint4(uh[0],uh[1],uh[2],uh[3]);
            ((uint4*)ph)[1] = make_uint4(uh[4],uh[5],uh[6],uh[7]);
            ((uint4*)pl)[0] = make_uint4(ul[0],ul[1],ul[2],ul[3]);
            ((uint4*)pl)[1] = make_uint4(ul[4],ul[5],ul[6],ul[7]);
        }
        #pragma unroll
        for (int it = 0; it < 2; ++it) {   // ---- stage B (128x32): copies ----
            const int idx = tid + it * 256;            // 0..511
            const int br = idx >> 2, bk = (idx & 3) << 3;
            const size_t uoff = (size_t)(nc0 + br) * (K >> 1) + ((k0 + bk) >> 1);
            *(uint4*)(BsH + br * ASTR + (bk >> 1)) = *(const uint4*)(Wh + uoff);
            *(uint4*)(BsL + br * ASTR + (bk >> 1)) = *(const uint4*)(Wl + uoff);
        }
        __syncthreads();

        half8 bhv[4], blv[4];
        #pragma unroll
        for (int ct = 0; ct < 4; ++ct) {
            const int br = wc + ct * 16 + lr;
            bhv[ct] = *(const half8*)((const char*)BsH + br * 80 + lq * 16);
            blv[ct] = *(const half8*)((const char*)BsL + br * 80 + lq * 16);
        }
        #pragma unroll
        for (int rt = 0; rt < 4; ++rt) {
            const int ar = wr + rt * 16 + lr;
            const half8 ah = *(const half8*)((const char*)AsH + ar * 80 + lq * 16);
            const half8 al = *(const half8*)((const char*)AsL + ar * 80 + lq * 16);
            #pragma unroll
            for (int ct = 0; ct < 4; ++ct) {
                acc[rt][ct] = __builtin_amdgcn_mfma_f32_16x16x32_f16(ah, bhv[ct], acc[rt][ct], 0, 0, 0);
                acc[rt][ct] = __builtin_amdgcn_mfma_f32_16x16x32_f16(ah, blv[ct], acc[rt][ct], 0, 0, 0);
                acc[rt][ct] = __builtin_amdgcn_mfma_f32_16x16x32_f16(al, bhv[ct], acc[rt][ct], 0, 0, 0);
            }
        }
        __syncthreads();
    }

    float* pout = Part + (size_t)ks * ((size_t)Mtot * EDIM);
    const float sc = 1.0f / 1024.0f;
    #pragma unroll
    for (int rt = 0; rt < 4; ++rt) {
        #pragma unroll
        for (int r = 0; r < 4; ++r) {
            const int grr = m0 + wr + rt * 16 + lq * 4 + r;
            if (grr >= Mtot) continue;
            #pragma unroll
            for (int ct = 0; ct < 4; ++ct)
                pout[(size_t)grr * EDIM + nc0 + wc + ct * 16 + lr] = acc[rt][ct][r] * sc;
        }
    }
}

// ---------------------------------------------------------------------------
// Reduce split-K partials + bias + relu -> fp16 hi/lo planes of H.
// ---------------------------------------------------------------------------
__global__ __launch_bounds__(256)
void k_reduce_bias_relu(const float* __restrict__ Part,
                        const float* __restrict__ bias,
                        unsigned* __restrict__ Hh, unsigned* __restrict__ Hl,
                        int S, size_t MN4) {
    const size_t i = (size_t)blockIdx.x * blockDim.x + threadIdx.x;
    const size_t stride = (size_t)gridDim.x * blockDim.x;
    const size_t MN = MN4 * 4;
    for (size_t i4 = i; i4 < MN4; i4 += stride) {
        float4 s = ((const float4*)Part)[i4];
        for (int z = 1; z < S; ++z)
            { const float4 q = ((const float4*)(Part + (size_t)z * MN))[i4];
              s.x += q.x; s.y += q.y; s.z += q.z; s.w += q.w; }
        const float4 b = ((const float4*)bias)[i4 & 63];
        s.x = fmaxf(s.x + b.x, 0.f); s.y = fmaxf(s.y + b.y, 0.f);
        s.z = fmaxf(s.z + b.z, 0.f); s.w = fmaxf(s.w + b.w, 0.f);
        const _Float16 hx = (_Float16)s.x, hy = (_Float16)s.y;
        const _Float16 hz = (_Float16)s.z, hw = (_Float16)s.w;
        Hh[i4*2+0] = pk2h(hx, hy);
        Hh[i4*2+1] = pk2h(hz, hw);
        Hl[i4*2+0] = pk2h((_Float16)(s.x - (float)hx), (_Float16)(s.y - (float)hy));
        Hl[i4*2+1] = pk2h((_Float16)(s.z - (float)hz), (_Float16)(s.w - (float)hw));
    }
}

// ---------------------------------------------------------------------------
// Pure-fp16 GEMM (planes in), fused bias+relu, emits Emb as fp16 hi/lo planes.
// BM=64 x BN=256 (K=256, one shot).
// ---------------------------------------------------------------------------
__global__ __launch_bounds__(256)
void k_gemm_f16(const unsigned* __restrict__ Ah, const unsigned* __restrict__ Al,
                const unsigned* __restrict__ Wh, const unsigned* __restrict__ Wl,
                const float* __restrict__ bias,
                unsigned* __restrict__ Eh, unsigned* __restrict__ El,
                int Mtot, int K) {
    __shared__ alignas(16) unsigned AsH[64 * ASTR],  AsL[64 * ASTR];
    __shared__ alignas(16) unsigned BsH[256 * ASTR], BsL[256 * ASTR];
    const int tid = threadIdx.x;
    const int m0  = blockIdx.x * 64;

    const int sar = tid >> 2, sak = (tid & 3) << 3;
    const int gr  = m0 + sar;
    const bool arow = (gr < Mtot);

    const int lane = tid & 63, wv = tid >> 6;
    const int wc = wv << 6;
    const int lr = lane & 15, lq = lane >> 4;

    f32x4 acc[4][4] = {};

    for (int k0 = 0; k0 < K; k0 += 32) {
        {
            uint4 vh = make_uint4(0,0,0,0), vl = vh;
            if (arow) {
                const size_t uoff = (size_t)gr * (K >> 1) + ((k0 + sak) >> 1);
                vh = *(const uint4*)(Ah + uoff);
                vl = *(const uint4*)(Al + uoff);
            }
            *(uint4*)(AsH + sar * ASTR + (sak >> 1)) = vh;
            *(uint4*)(AsL + sar * ASTR + (sak >> 1)) = vl;
        }
        #pragma unroll
        for (int it = 0; it < 4; ++it) {
            const int idx = tid + it * 256;
            const int br = idx >> 2, bk = (idx & 3) << 3;
            const size_t uoff = (size_t)br * (K >> 1) + ((k0 + bk) >> 1);
            *(uint4*)(BsH + br * ASTR + (bk >> 1)) = *(const uint4*)(Wh + uoff);
            *(uint4*)(BsL + br * ASTR + (bk >> 1)) = *(const uint4*)(Wl + uoff);
        }
        __syncthreads();

        half8 bhv[4], blv[4];
        #pragma unroll
        for (int ct = 0; ct < 4; ++ct) {
            const int br = wc + ct * 16 + lr;
            bhv[ct] = *(const half8*)((const char*)BsH + br * 80 + lq * 16);
            blv[ct] = *(const half8*)((const char*)BsL + br * 80 + lq * 16);
        }
        #pragma unroll
        for (int rt = 0; rt < 4; ++rt) {
            const int ar = rt * 16 + lr;
            const half8 ah = *(const half8*)((const char*)AsH + ar * 80 + lq * 16);
            const half8 al = *(const half8*)((const char*)AsL + ar * 80 + lq * 16);
            #pragma unroll
            for (int ct = 0; ct < 4; ++ct) {
                acc[rt][ct] = __builtin_amdgcn_mfma_f32_16x16x32_f16(ah, bhv[ct], acc[rt][ct], 0, 0, 0);
                acc[rt][ct] = __builtin_amdgcn_mfma_f32_16x16x32_f16(ah, blv[ct], acc[rt][ct], 0, 0, 0);
                acc[rt][ct] = __builtin_amdgcn_mfma_f32_16x16x32_f16(al, bhv[ct], acc[rt][ct], 0, 0, 0);
            }
        }
        __syncthreads();
    }

    _Float16* ph = (_Float16*)Eh;
    _Float16* pl = (_Float16*)El;
    const float sc = 1.0f / 1024.0f;
    #pragma unroll
    for (int rt = 0; rt < 4; ++rt) {
        #pragma unroll
        for (int r = 0; r < 4; ++r) {
            const int grr = m0 + rt * 16 + lq * 4 + r;
            if (grr >= Mtot) continue;
            #pragma unroll
            for (int ct = 0; ct < 4; ++ct) {
                const int gc = wc + ct * 16 + lr;
                const float vv = fmaxf(acc[rt][ct][r] * sc + bias[gc], 0.0f);
                const _Float16 hv = (_Float16)vv;
                ph[(size_t)grr * EDIM + gc] = hv;
                pl[(size_t)grr * EDIM + gc] = (_Float16)(vv - (float)hv);
            }
        }
    }
}

// ---------------------------------------------------------------------------
// Direct fp32 GEMM (NT, fused bias+relu) — fallback only (ws too small).
// ---------------------------------------------------------------------------
__global__ __launch_bounds__(256)
void k_embed_gemm(const float* __restrict__ S0, int n0,
                  const float* __restrict__ S1, int n1,
                  const float* __restrict__ S2,
                  const float* __restrict__ W, const float* __restrict__ bias,
                  float* __restrict__ C, int Mtot, int K) {
    __shared__ alignas(16) float As[16][68];
    __shared__ alignas(16) float Bs[16][68];
    const int tid  = threadIdx.x;
    const int tx   = tid & 15, ty = tid >> 4;
    const int m0   = blockIdx.x * 64, nc0 = blockIdx.y * 64;
    const int lrow = tid >> 2;
    const int lk4  = (tid & 3) << 2;

    const int gr = m0 + lrow;
    const float* srow = nullptr;
    if (gr < n0)            srow = S0 + (size_t)gr * K;
    else if (gr < n0 + n1)  srow = S1 + (size_t)(gr - n0) * K;
    else if (gr < Mtot)     srow = S2;
    const float* wrow = W + (size_t)(nc0 + lrow) * K;

    float acc[4][4] = {};
    for (int k0 = 0; k0 < K; k0 += 16) {
        float4 va = make_float4(0.f, 0.f, 0.f, 0.f);
        if (srow) va = *(const float4*)(srow + k0 + lk4);
        const float4 vb = *(const float4*)(wrow + k0 + lk4);
        As[lk4+0][lrow] = va.x; As[lk4+1][lrow] = va.y;
        As[lk4+2][lrow] = va.z; As[lk4+3][lrow] = va.w;
        Bs[lk4+0][lrow] = vb.x; Bs[lk4+1][lrow] = vb.y;
        Bs[lk4+2][lrow] = vb.z; Bs[lk4+3][lrow] = vb.w;
        __syncthreads();
        #pragma unroll
        for (int kk = 0; kk < 16; ++kk) {
            const float4 a4 = *(const float4*)&As[kk][ty << 2];
            const float4 b4 = *(const float4*)&Bs[kk][tx << 2];
            const float av[4] = {a4.x, a4.y, a4.z, a4.w};
            const float bv[4] = {b4.x, b4.y, b4.z, b4.w};
            #pragma unroll
            for (int i2 = 0; i2 < 4; ++i2)
                #pragma unroll
                for (int j2 = 0; j2 < 4; ++j2)
                    acc[i2][j2] = fmaf(av[i2], bv[j2], acc[i2][j2]);
        }
        __syncthreads();
    }
    #pragma unroll
    for (int i2 = 0; i2 < 4; ++i2) {
        const int grr = m0 + (ty << 2) + i2;
        if (grr >= Mtot) continue;
        #pragma unroll
        for (int j2 = 0; j2 < 4; ++j2) {
            const int gc = nc0 + (tx << 2) + j2;
            const float vv = acc[i2][j2] + bias[gc];
            C[(size_t)grr * EDIM + gc] = fmaxf(vv, 0.0f);
        }
    }
}

// ---------------------------------------------------------------------------
// Per-pair scaled edit-cost matrix via MFMA Gram; staging = plane copies,
// norms precomputed.
// ---------------------------------------------------------------------------
#define CSTR 36
__global__ __launch_bounds__(256)
void k_costs(const unsigned* __restrict__ Eh, const unsigned* __restrict__ El,
             const float* __restrict__ Norms,
             const int* __restrict__ len_s, const int* __restrict__ len_t,
             int Ns, int Nt, float* __restrict__ costs) {
    __shared__ alignas(16) unsigned Ah[34 * CSTR], Al[34 * CSTR];
    __shared__ alignas(16) unsigned Bh[34 * CSTR], Bl[34 * CSTR];
    __shared__ float dtile[LMAXP1 * LMAXP1];
    __shared__ float na[LMAXP1], nb[LMAXP1];
    __shared__ float red[256];
    __shared__ float s_scale;
    const int p = blockIdx.x, tid = threadIdx.x;
    const int n = len_s[p], m = len_t[p];
    int offs = 0, offt = 0;
    for (int j = 0; j < p; ++j) { offs += len_s[j]; offt += len_t[j]; }  // uniform
    const int veRow = Ns + Nt;
    const int tbase = Ns + offt;

    const int lane = tid & 63, wv = tid >> 6;
    const int lr = lane & 15, lq = lane >> 4;

    if (tid <= n)                       na[tid] = Norms[(tid < n) ? offs + tid : veRow];
    else if (tid >= 64 && tid - 64 <= m) nb[tid - 64] = Norms[(tid - 64 < m) ? tbase + tid - 64 : veRow];

    f32x4 g0 = {}, g1 = {}, g2 = {};
    const int t0 = wv, t1 = wv + 4, t2 = wv + 8;

    for (int k0 = 0; k0 < EDIM; k0 += 64) {
        for (int idx = tid; idx < 34 * 16; idx += 256) {
            const int r = idx >> 4, c4 = idx & 15;
            const int rowA = (r < n) ? offs + r : ((r == n) ? veRow : -1);
            const int rowB = (r < m) ? tbase + r : ((r == m) ? veRow : -1);
            uint2 vah = make_uint2(0,0), val = vah, vbh = vah, vbl = vah;
            if (rowA >= 0) {
                const size_t uo_ = (size_t)rowA * 128 + (k0 >> 1) + c4 * 2;
                vah = *(const uint2*)(Eh + uo_); val = *(const uint2*)(El + uo_);
            }
            if (rowB >= 0) {
                const size_t uo_ = (size_t)rowB * 128 + (k0 >> 1) + c4 * 2;
                vbh = *(const uint2*)(Eh + uo_); vbl = *(const uint2*)(El + uo_);
            }
            const int uo = r * CSTR + c4 * 2;
            *(uint2*)(Ah + uo) = vah; *(uint2*)(Al + uo) = val;
            *(uint2*)(Bh + uo) = vbh; *(uint2*)(Bl + uo) = vbl;
        }
        __syncthreads();

        #pragma unroll
        for (int kf = 0; kf < 2; ++kf) {
#define GRAM_TILE(T, G) { \
            const int tr_ = (T) / 3, tc_ = (T) % 3;                              \
            const int ar_ = tr_ * 16 + lr, br_ = tc_ * 16 + lr;                  \
            const half8 ah = *(const half8*)((const char*)Ah + ar_*144 + kf*64 + lq*16); \
            const half8 al = *(const half8*)((const char*)Al + ar_*144 + kf*64 + lq*16); \
            const half8 bh = *(const half8*)((const char*)Bh + br_*144 + kf*64 + lq*16); \
            const half8 bl = *(const half8*)((const char*)Bl + br_*144 + kf*64 + lq*16); \
            G = __builtin_amdgcn_mfma_f32_16x16x32_f16(ah, bh, G, 0, 0, 0);      \
            G = __builtin_amdgcn_mfma_f32_16x16x32_f16(ah, bl, G, 0, 0, 0);      \
            G = __builtin_amdgcn_mfma_f32_16x16x32_f16(al, bh, G, 0, 0, 0); }
            GRAM_TILE(t0, g0)
            GRAM_TILE(t1, g1)
            if (wv == 0) GRAM_TILE(t2, g2)
#undef GRAM_TILE
        }
        __syncthreads();
    }

#define DTILE_OUT(T, G) { \
    const int tr_ = (T) / 3, tc_ = (T) % 3;                                      \
    _Pragma("unroll")                                                            \
    for (int r = 0; r < 4; ++r) {                                                \
        const int i_ = tr_ * 16 + lq * 4 + r, j_ = tc_ * 16 + lr;                \
        if (i_ <= n && j_ <= m) {                                                \
            const float sq = fmaxf(na[i_] + nb[j_] - 2.0f * G[r], 0.0f);         \
            dtile[i_ * LMAXP1 + j_] = (sq > 0.0f) ? sqrtf(sq) : 0.0f;            \
        } } }
    DTILE_OUT(t0, g0)
    DTILE_OUT(t1, g1)
    if (wv == 0) DTILE_OUT(t2, g2)
#undef DTILE_OUT
    __syncthreads();

    float lsum = 0.f;
    const int m1 = m + 1;
    const int cells = (n + 1) * m1;
    for (int c = tid; c < cells; c += 256) {
        const int i = c / m1, j = c - i * m1;
        lsum += dtile[i * LMAXP1 + j];
    }
    red[tid] = lsum;
    __syncthreads();
    for (int s = 128; s > 0; s >>= 1) {
        if (tid < s) red[tid] += red[tid + s];
        __syncthreads();
    }
    if (tid == 0) s_scale = (float)(n * m) / red[0];
    __syncthreads();
    const float scale = s_scale;
    for (int idx = tid; idx < LMAXP1 * LMAXP1; idx += 256) {
        const int i = idx / LMAXP1, j = idx - i * LMAXP1;
        const float v = (i <= n && j <= m) ? dtile[i * LMAXP1 + j] * scale : 0.0f;
        costs[(size_t)p * (LMAXP1 * LMAXP1) + idx] = v;
    }
}

// ---------------------------------------------------------------------------
// LAP: reduced max(n,m)^2 LAP; col-reduction/greedy + ARR + JV Dijkstra.
// (R17-verified exact: absmax 0.0)
// ---------------------------------------------------------------------------
__device__ inline int rdlane_i(int v, int l) { return __builtin_amdgcn_readlane(v, l); }
__device__ inline float rdlane_f(float v, int l) {
    return __int_as_float(__builtin_amdgcn_readlane(__float_as_int(v), l));
}
__device__ inline unsigned wave_umin64(unsigned x) {
#define DPPMINU(ctrl) { unsigned t_ = (unsigned)__builtin_amdgcn_update_dpp(  \
        (int)x, (int)x, (ctrl), 0xf, 0xf, false);                             \
        x = (t_ < x) ? t_ : x; }
    DPPMINU(0xB1)
    DPPMINU(0x4E)
    DPPMINU(0x141)
    DPPMINU(0x140)
    DPPMINU(0x142)
    DPPMINU(0x143)
#undef DPPMINU
    return (unsigned)__builtin_amdgcn_readlane((int)x, 63);
}

__global__ __launch_bounds__(64)
void k_lap(const float* __restrict__ costs, const int* __restrict__ len_s,
           const int* __restrict__ len_t, float* __restrict__ aligns,
           float* __restrict__ geds) {
    __shared__ float ec[LMAXP1 * LMAXP1];
    __shared__ float Ms[33 * 64];
    const int p = blockIdx.x, lane = threadIdx.x;
    const int n = len_s[p], m = len_t[p];
    const float* cp = costs + (size_t)p * (LMAXP1 * LMAXP1);
    for (int idx = lane; idx < LMAXP1 * LMAXP1; idx += 64) ec[idx] = cp[idx];
    __syncthreads();

    const bool swp = (n > m);
    const int R  = swp ? n : m;
    const int S_ = swp ? m : n;
    const bool vec = (lane >= 1 && lane <= R);

    for (int r = 1; r <= R; ++r) {
        float cv = FBIG;
        const int i0b = r - 1, j0b = lane - 1;
        if (vec) {
            if (!swp) {
                const float ins = ec[n * LMAXP1 + j0b];
                cv = (i0b < S_)
                   ? fminf(ec[i0b * LMAXP1 + j0b], ec[i0b * LMAXP1 + m] + ins)
                   : ins;
            } else {
                const float ins = ec[j0b * LMAXP1 + m];
                cv = (i0b < S_)
                   ? fminf(ec[j0b * LMAXP1 + i0b], ec[n * LMAXP1 + i0b] + ins)
                   : ins;
            }
        }
        Ms[(r << 6) + lane] = cv;
    }
    __syncthreads();

    // ---- column reduction + greedy ----
    float v_l = 0.0f;
    int amin_l = 0;
    if (vec) {
        float best = FBIG;
        for (int r = 1; r <= R; ++r) {
            const float c = Ms[(r << 6) + lane];
            if (c < best) { best = c; amin_l = r; }
        }
        v_l = best;
    }
    int p_l = 0;
    unsigned long long rowfree = ((1ull << R) - 1ull) << 1;
    for (int j = 1; j <= R; ++j) {
        const int ai = rdlane_i(amin_l, j);
        if ((rowfree >> ai) & 1ull) {
            if (lane == j) p_l = ai;
            rowfree &= ~(1ull << ai);
        }
    }

    // ---- augmenting row reduction (ARR) ----
    float ucol = 0.0f;
    {
        unsigned long long q = rowfree;
        int pops = 0;
        const int cap = 3 * R;
        while (q && pops < cap) {
            const int i = __ffsll(q) - 1;
            q &= ~(1ull << i);
            ++pops;
            const float rc = vec ? fmaxf(Ms[(i << 6) + lane] - v_l, 0.0f) : FBIG;
            const unsigned key = (__float_as_uint(rc) & ~63u) | (unsigned)lane;
            const unsigned k1 = wave_umin64(key);
            int j1 = (int)(k1 & 63u);
            const float min1 = rdlane_f(rc, j1);
            const unsigned key2 = (lane == j1) ? 0xFFFFFFFFu : key;
            const unsigned k2 = wave_umin64(key2);
            const float min2 = rdlane_f(rc, (int)(k2 & 63u));
            int owner = rdlane_i(p_l, j1);
            const bool strict = (min1 < min2);
            if (!strict) {
                const unsigned long long ball =
                    __ballot(vec && (rc == min1) && (p_l == 0));
                if (ball == 0ull) continue;
                j1 = __ffsll(ball) - 1;
                j1 = __builtin_amdgcn_readfirstlane(j1);
                owner = 0;
            }
            if (lane == j1) {
                p_l = i; ucol = min2;
                if (strict) v_l -= (min2 - min1);
            }
            rowfree &= ~(1ull << i);
            if (owner != 0) { rowfree |= (1ull << owner); q |= (1ull << owner); }
        }
    }

    // ---- JV Dijkstra for remaining free rows ----
    float minv_l = FBIG;
    int way_l = 0;

    for (int i = 1; i <= R; ++i) {
        if (!((rowfree >> i) & 1ull)) continue;
        if (lane == 0) { p_l = i; ucol = 0.0f; }
        minv_l = FBIG;
        int used_l = 0;
        int j0 = 0, i0 = i;
        float u_i0 = 0.0f;
        while (true) {
            if (lane == j0) used_l = 1;
            const float cur = Ms[(i0 << 6) + lane] - u_i0 - v_l;
            const bool unused = vec && !used_l;
            if (unused && cur < minv_l) { minv_l = cur; way_l = j0; }
            const float mval = unused ? fmaxf(minv_l, 0.0f) : FBIG;
            const unsigned key = (__float_as_uint(mval) & ~63u) | (unsigned)lane;
            const unsigned kmin = wave_umin64(key);
            const int j1 = (int)(kmin & 63u);
            const float delta = rdlane_f(minv_l, j1);
            if (used_l) { ucol += delta; v_l -= delta; }
            if (unused) minv_l -= delta;
            j0 = j1;
            i0 = rdlane_i(p_l, j1);
            u_i0 = rdlane_f(ucol, j1);
            if (i0 == 0) break;
        }
        int jj = j0;
        while (jj != 0) {
            const int   j1a = rdlane_i(way_l, jj);
            const int   pn  = rdlane_i(p_l, j1a);
            const float un  = rdlane_f(ucol, j1a);
            if (lane == jj) { p_l = pn; ucol = un; }
            jj = j1a;
        }
    }

    // ---- decode ----
    float* ap = aligns + (size_t)p * (LMAXP1 * LMAXP1);
    for (int idx = lane; idx < LMAXP1 * LMAXP1; idx += 64) ap[idx] = 0.0f;
    __syncthreads();
    float gedv = 0.0f;
    if (vec) {
        const int i0b = p_l - 1;
        const int j0b = lane - 1;
        if (!swp) {
            if (i0b < S_) {
                const float sub = ec[i0b * LMAXP1 + j0b];
                const float alt = ec[i0b * LMAXP1 + m] + ec[n * LMAXP1 + j0b];
                if (sub <= alt) { ap[i0b * LMAXP1 + j0b] = 1.0f; gedv = sub; }
                else { ap[i0b * LMAXP1 + m] = 1.0f;
                       ap[n * LMAXP1 + j0b] = 1.0f;
                       gedv = alt; }
            } else {
                ap[n * LMAXP1 + j0b] = 1.0f;
                gedv = ec[n * LMAXP1 + j0b];
            }
        } else {
            if (i0b < S_) {
                const float sub = ec[j0b * LMAXP1 + i0b];
                const float alt = ec[n * LMAXP1 + i0b] + ec[j0b * LMAXP1 + m];
                if (sub <= alt) { ap[j0b * LMAXP1 + i0b] = 1.0f; gedv = sub; }
                else { ap[n * LMAXP1 + i0b] = 1.0f;
                       ap[j0b * LMAXP1 + m] = 1.0f;
                       gedv = alt; }
            } else {
                ap[j0b * LMAXP1 + m] = 1.0f;
                gedv = ec[j0b * LMAXP1 + m];
            }
        }
    }
    #pragma unroll
    for (int off = 32; off > 0; off >>= 1) gedv += __shfl_xor(gedv, off);
    if (lane == 0) geds[p] = gedv / (float)(n + m);
}

// ---------------------------------------------------------------------------
extern "C" void kernel_launch(void* const* d_in, const int* in_sizes, int n_in,
                              void* d_out, int out_size, void* d_ws, size_t ws_size,
                              hipStream_t stream) {
    const float* x_s = (const float*)d_in[0];
    const float* x_t = (const float*)d_in[1];
    const float* W1  = (const float*)d_in[2];
    const float* b1  = (const float*)d_in[3];
    const float* W2  = (const float*)d_in[4];
    const float* b2  = (const float*)d_in[5];
    const float* ve  = (const float*)d_in[6];
    const int* len_s = (const int*)d_in[7];
    const int* len_t = (const int*)d_in[8];
    const int P    = in_sizes[7];
    const int Ns   = in_sizes[0] / 2048;
    const int Nt   = in_sizes[1] / 2048;
    const int Mtot = Ns + Nt + 1;
    const size_t MN  = (size_t)Mtot * EDIM;          // even

    float* out_aligns = (float*)d_out;
    float* out_costs  = out_aligns + (size_t)P * LMAXP1 * LMAXP1;
    float* out_geds   = out_costs  + (size_t)P * LMAXP1 * LMAXP1;

    const dim3 b256(256);
    const int gx64  = (Mtot + 63) / 64;
    const int gx128 = (Mtot + 127) / 128;
    const int gnorm = (Mtot + 3) / 4;

    const size_t fixed = MN + 10240 + 2 * 262144 + 2 * 32768;
    int S = 0;
    if (ws_size >= (4 * MN + fixed) * sizeof(float)) S = 4;
    else if (ws_size >= (2 * MN + fixed) * sizeof(float)) S = 2;

    if (S > 0) {
        float* Part = (float*)d_ws;
        unsigned* Eh  = (unsigned*)Part;              // MN/2 uints (alias)
        unsigned* El  = Eh + MN / 2;
        unsigned* Hh  = (unsigned*)(Part + (size_t)S * MN);
        unsigned* Hl  = Hh + MN / 2;
        float* Norms  = (float*)(Hl + MN / 2);
        unsigned* W1h = (unsigned*)(Norms + 10240);
        unsigned* W1l = W1h + 262144;
        unsigned* W2h = W1l + 262144;
        unsigned* W2l = W2h + 32768;

        k_convw<<<dim3(1024), b256, 0, stream>>>(W1, W1h, W1l, 262144, 1024.0f);
        k_convw<<<dim3(128),  b256, 0, stream>>>(W2, W2h, W2l, 32768, 1024.0f);

        k_gemm_splitk<<<dim3(gx128, 2, S), b256, 0, stream>>>(
            x_s, Ns, x_t, Nt, ve, W1h, W1l, Part, Mtot, 2048, 2048 / S);

        const size_t MN4 = MN / 4;
        const int rblocks = (int)((MN4 + 255) / 256) < 2048
                          ? (int)((MN4 + 255) / 256) : 2048;
        k_reduce_bias_relu<<<dim3(rblocks), b256, 0, stream>>>(Part, b1, Hh, Hl, S, MN4);

        k_gemm_f16<<<dim3(gx64), b256, 0, stream>>>(Hh, Hl, W2h, W2l, b2, Eh, El, Mtot, 256);
        k_norms<<<dim3(gnorm), b256, 0, stream>>>(Eh, El, Norms, Mtot);

        k_costs<<<dim3(P), b256, 0, stream>>>(Eh, El, Norms, len_s, len_t, Ns, Nt, out_costs);
        k_lap<<<dim3(P), dim3(64), 0, stream>>>(out_costs, len_s, len_t, out_aligns, out_geds);
    } else {
        float* H   = (float*)d_ws;
        float* Emb = H + MN;
        unsigned* Eh = (unsigned*)(Emb + MN);
        unsigned* El = Eh + MN / 2;
        float* Norms = (float*)(El + MN / 2);
        k_embed_gemm<<<dim3(gx64, 4), b256, 0, stream>>>(
            x_s, Ns, x_t, Nt, ve, W1, b1, H, Mtot, 2048);
        k_embed_gemm<<<dim3(gx64, 4), b256, 0, stream>>>(
            H, Mtot, nullptr, 0, nullptr, W2, b2, Emb, Mtot, 256);
        k_convw<<<dim3(1024), b256, 0, stream>>>(Emb, Eh, El, (int)(MN / 2), 1.0f);
        k_norms<<<dim3(gnorm), b256, 0, stream>>>(Eh, El, Norms, Mtot);
        k_costs<<<dim3(P), b256, 0, stream>>>(Eh, El, Norms, len_s, len_t, Ns, Nt, out_costs);
        k_lap<<<dim3(P), dim3(64), 0, stream>>>(out_costs, len_s, len_t, out_aligns, out_geds);
    }
}

// Round 22
// 164.381 us; speedup vs baseline: 1.0539x; 1.0026x over previous
//
#include <hip/hip_runtime.h>
#include <math.h>

#define LMAXP1 33
#define EDIM   256
#define FBIG   3.0e38f

typedef _Float16 half8 __attribute__((ext_vector_type(8)));
typedef float    f32x4 __attribute__((ext_vector_type(4)));

__device__ inline unsigned pk2h(_Float16 a, _Float16 b) {
    union { _Float16 h[2]; unsigned u; } q; q.h[0] = a; q.h[1] = b; return q.u;
}

// ---------------------------------------------------------------------------
// Convert fp32 matrix -> fp16 hi/lo planes with scale.
// ---------------------------------------------------------------------------
__global__ __launch_bounds__(256)
void k_convw(const float* __restrict__ W, unsigned* __restrict__ Wh,
             unsigned* __restrict__ Wl, int npairs, float scale) {
    const int stride = gridDim.x * blockDim.x;
    for (int i = blockIdx.x * blockDim.x + threadIdx.x; i < npairs; i += stride) {
        const float a0 = W[2*i] * scale, a1 = W[2*i+1] * scale;
        const _Float16 h0 = (_Float16)a0, h1 = (_Float16)a1;
        const _Float16 l0 = (_Float16)(a0 - (float)h0);
        const _Float16 l1 = (_Float16)(a1 - (float)h1);
        Wh[i] = pk2h(h0, h1); Wl[i] = pk2h(l0, l1);
    }
}

// ---------------------------------------------------------------------------
// Row norms from fp16 planes: Norms[row] = sum((hi+lo)^2). 1 wave per row.
// ---------------------------------------------------------------------------
__global__ __launch_bounds__(256)
void k_norms(const unsigned* __restrict__ Eh, const unsigned* __restrict__ El,
             float* __restrict__ Norms, int Mtot) {
    const int row  = blockIdx.x * 4 + (threadIdx.x >> 6);
    const int lane = threadIdx.x & 63;
    if (row >= Mtot) return;
    const uint2 h2 = *(const uint2*)(Eh + (size_t)row * 128 + lane * 2);
    const uint2 l2 = *(const uint2*)(El + (size_t)row * 128 + lane * 2);
    union { unsigned u; _Float16 h[2]; } qh, ql;
    float s = 0.f;
    qh.u = h2.x; ql.u = l2.x;
    { const float x0 = (float)qh.h[0] + (float)ql.h[0];
      const float x1 = (float)qh.h[1] + (float)ql.h[1];
      s = fmaf(x0, x0, s); s = fmaf(x1, x1, s); }
    qh.u = h2.y; ql.u = l2.y;
    { const float x0 = (float)qh.h[0] + (float)ql.h[0];
      const float x1 = (float)qh.h[1] + (float)ql.h[1];
      s = fmaf(x0, x0, s); s = fmaf(x1, x1, s); }
    #pragma unroll
    for (int off = 32; off > 0; off >>= 1) s += __shfl_xor(s, off);
    if (lane == 0) Norms[row] = s;
}

// ---------------------------------------------------------------------------
// Split-K GEMM (NT) via fp16-split MFMA, BM=128 x BN=128 (R20-proven).
// ---------------------------------------------------------------------------
#define ASTR 20   // uints per LDS k-row (80B)
__global__ __launch_bounds__(256)
void k_gemm_splitk(const float* __restrict__ S0, int n0,
                   const float* __restrict__ S1, int n1,
                   const float* __restrict__ S2,
                   const unsigned* __restrict__ Wh, const unsigned* __restrict__ Wl,
                   float* __restrict__ Part, int Mtot, int K, int kchunk) {
    __shared__ alignas(16) unsigned AsH[128 * ASTR], AsL[128 * ASTR];
    __shared__ alignas(16) unsigned BsH[128 * ASTR], BsL[128 * ASTR];
    const int tid = threadIdx.x;
    const int m0  = blockIdx.x * 128;
    const int nc0 = blockIdx.y * 128;
    const int ks  = blockIdx.z;
    const int kb  = ks * kchunk;
    const int ke  = (kb + kchunk < K) ? kb + kchunk : K;

    const int sar = tid >> 1;              // A row 0..127
    const int sak = (tid & 1) << 4;        // A k-offset 0/16
    const int gr  = m0 + sar;
    const float* srow = nullptr;
    if (gr < n0)            srow = S0 + (size_t)gr * K;
    else if (gr < n0 + n1)  srow = S1 + (size_t)(gr - n0) * K;
    else if (gr < Mtot)     srow = S2;

    const int lane = tid & 63, wv = tid >> 6;
    const int wr = (wv & 1) << 6;          // wave row base 0/64
    const int wc = (wv >> 1) << 6;         // wave col base 0/64
    const int lr = lane & 15, lq = lane >> 4;

    f32x4 acc[4][4] = {};

    for (int k0 = kb; k0 < ke; k0 += 32) {
        {   // ---- stage A (128x32 fp32 -> hi/lo fp16), 16 elems/thread ----
            float x[16];
            if (srow) {
                const float4 f0 = *(const float4*)(srow + k0 + sak + 0);
                const float4 f1 = *(const float4*)(srow + k0 + sak + 4);
                const float4 f2 = *(const float4*)(srow + k0 + sak + 8);
                const float4 f3 = *(const float4*)(srow + k0 + sak + 12);
                x[0]=f0.x; x[1]=f0.y; x[2]=f0.z; x[3]=f0.w;
                x[4]=f1.x; x[5]=f1.y; x[6]=f1.z; x[7]=f1.w;
                x[8]=f2.x; x[9]=f2.y; x[10]=f2.z; x[11]=f2.w;
                x[12]=f3.x; x[13]=f3.y; x[14]=f3.z; x[15]=f3.w;
            } else {
                #pragma unroll
                for (int j = 0; j < 16; ++j) x[j] = 0.f;
            }
            unsigned uh[8], ul[8];
            #pragma unroll
            for (int j = 0; j < 8; ++j) {
                const _Float16 h0 = (_Float16)x[2*j],   h1 = (_Float16)x[2*j+1];
                const _Float16 l0 = (_Float16)(x[2*j]   - (float)h0);
                const _Float16 l1 = (_Float16)(x[2*j+1] - (float)h1);
                uh[j] = pk2h(h0, h1); ul[j] = pk2h(l0, l1);
            }
            unsigned* ph = AsH + sar * ASTR + (sak >> 1);
            unsigned* pl = AsL + sar * ASTR + (sak >> 1);
            ((uint4*)ph)[0] = make_uint4(uh[0],uh[1],uh[2],uh[3]);
            ((uint4*)ph)[1] = make_uint4(uh[4],uh[5],uh[6],uh[7]);
            ((uint4*)pl)[0] = make_uint4(ul[0],ul[1],ul[2],ul[3]);
            ((uint4*)pl)[1] = make_uint4(ul[4],ul[5],ul[6],ul[7]);
        }
        #pragma unroll
        for (int it = 0; it < 2; ++it) {   // ---- stage B (128x32): copies ----
            const int idx = tid + it * 256;            // 0..511
            const int br = idx >> 2, bk = (idx & 3) << 3;
            const size_t uoff = (size_t)(nc0 + br) * (K >> 1) + ((k0 + bk) >> 1);
            *(uint4*)(BsH + br * ASTR + (bk >> 1)) = *(const uint4*)(Wh + uoff);
            *(uint4*)(BsL + br * ASTR + (bk >> 1)) = *(const uint4*)(Wl + uoff);
        }
        __syncthreads();

        half8 bhv[4], blv[4];
        #pragma unroll
        for (int ct = 0; ct < 4; ++ct) {
            const int br = wc + ct * 16 + lr;
            bhv[ct] = *(const half8*)((const char*)BsH + br * 80 + lq * 16);
            blv[ct] = *(const half8*)((const char*)BsL + br * 80 + lq * 16);
        }
        #pragma unroll
        for (int rt = 0; rt < 4; ++rt) {
            const int ar = wr + rt * 16 + lr;
            const half8 ah = *(const half8*)((const char*)AsH + ar * 80 + lq * 16);
            const half8 al = *(const half8*)((const char*)AsL + ar * 80 + lq * 16);
            #pragma unroll
            for (int ct = 0; ct < 4; ++ct) {
                acc[rt][ct] = __builtin_amdgcn_mfma_f32_16x16x32_f16(ah, bhv[ct], acc[rt][ct], 0, 0, 0);
                acc[rt][ct] = __builtin_amdgcn_mfma_f32_16x16x32_f16(ah, blv[ct], acc[rt][ct], 0, 0, 0);
                acc[rt][ct] = __builtin_amdgcn_mfma_f32_16x16x32_f16(al, bhv[ct], acc[rt][ct], 0, 0, 0);
            }
        }
        __syncthreads();
    }

    float* pout = Part + (size_t)ks * ((size_t)Mtot * EDIM);
    const float sc = 1.0f / 1024.0f;
    #pragma unroll
    for (int rt = 0; rt < 4; ++rt) {
        #pragma unroll
        for (int r = 0; r < 4; ++r) {
            const int grr = m0 + wr + rt * 16 + lq * 4 + r;
            if (grr >= Mtot) continue;
            #pragma unroll
            for (int ct = 0; ct < 4; ++ct)
                pout[(size_t)grr * EDIM + nc0 + wc + ct * 16 + lr] = acc[rt][ct][r] * sc;
        }
    }
}

// ---------------------------------------------------------------------------
// Reduce split-K partials + bias + relu -> fp16 hi/lo planes of H.
// ---------------------------------------------------------------------------
__global__ __launch_bounds__(256)
void k_reduce_bias_relu(const float* __restrict__ Part,
                        const float* __restrict__ bias,
                        unsigned* __restrict__ Hh, unsigned* __restrict__ Hl,
                        int S, size_t MN4) {
    const size_t i = (size_t)blockIdx.x * blockDim.x + threadIdx.x;
    const size_t stride = (size_t)gridDim.x * blockDim.x;
    const size_t MN = MN4 * 4;
    for (size_t i4 = i; i4 < MN4; i4 += stride) {
        float4 s = ((const float4*)Part)[i4];
        for (int z = 1; z < S; ++z)
            { const float4 q = ((const float4*)(Part + (size_t)z * MN))[i4];
              s.x += q.x; s.y += q.y; s.z += q.z; s.w += q.w; }
        const float4 b = ((const float4*)bias)[i4 & 63];
        s.x = fmaxf(s.x + b.x, 0.f); s.y = fmaxf(s.y + b.y, 0.f);
        s.z = fmaxf(s.z + b.z, 0.f); s.w = fmaxf(s.w + b.w, 0.f);
        const _Float16 hx = (_Float16)s.x, hy = (_Float16)s.y;
        const _Float16 hz = (_Float16)s.z, hw = (_Float16)s.w;
        Hh[i4*2+0] = pk2h(hx, hy);
        Hh[i4*2+1] = pk2h(hz, hw);
        Hl[i4*2+0] = pk2h((_Float16)(s.x - (float)hx), (_Float16)(s.y - (float)hy));
        Hl[i4*2+1] = pk2h((_Float16)(s.z - (float)hz), (_Float16)(s.w - (float)hw));
    }
}

// ---------------------------------------------------------------------------
// Pure-fp16 GEMM (planes in), fused bias+relu, emits Emb as fp16 hi/lo planes.
// ---------------------------------------------------------------------------
__global__ __launch_bounds__(256)
void k_gemm_f16(const unsigned* __restrict__ Ah, const unsigned* __restrict__ Al,
                const unsigned* __restrict__ Wh, const unsigned* __restrict__ Wl,
                const float* __restrict__ bias,
                unsigned* __restrict__ Eh, unsigned* __restrict__ El,
                int Mtot, int K) {
    __shared__ alignas(16) unsigned AsH[64 * ASTR],  AsL[64 * ASTR];
    __shared__ alignas(16) unsigned BsH[256 * ASTR], BsL[256 * ASTR];
    const int tid = threadIdx.x;
    const int m0  = blockIdx.x * 64;

    const int sar = tid >> 2, sak = (tid & 3) << 3;
    const int gr  = m0 + sar;
    const bool arow = (gr < Mtot);

    const int lane = tid & 63, wv = tid >> 6;
    const int wc = wv << 6;
    const int lr = lane & 15, lq = lane >> 4;

    f32x4 acc[4][4] = {};

    for (int k0 = 0; k0 < K; k0 += 32) {
        {
            uint4 vh = make_uint4(0,0,0,0), vl = vh;
            if (arow) {
                const size_t uoff = (size_t)gr * (K >> 1) + ((k0 + sak) >> 1);
                vh = *(const uint4*)(Ah + uoff);
                vl = *(const uint4*)(Al + uoff);
            }
            *(uint4*)(AsH + sar * ASTR + (sak >> 1)) = vh;
            *(uint4*)(AsL + sar * ASTR + (sak >> 1)) = vl;
        }
        #pragma unroll
        for (int it = 0; it < 4; ++it) {
            const int idx = tid + it * 256;
            const int br = idx >> 2, bk = (idx & 3) << 3;
            const size_t uoff = (size_t)br * (K >> 1) + ((k0 + bk) >> 1);
            *(uint4*)(BsH + br * ASTR + (bk >> 1)) = *(const uint4*)(Wh + uoff);
            *(uint4*)(BsL + br * ASTR + (bk >> 1)) = *(const uint4*)(Wl + uoff);
        }
        __syncthreads();

        half8 bhv[4], blv[4];
        #pragma unroll
        for (int ct = 0; ct < 4; ++ct) {
            const int br = wc + ct * 16 + lr;
            bhv[ct] = *(const half8*)((const char*)BsH + br * 80 + lq * 16);
            blv[ct] = *(const half8*)((const char*)BsL + br * 80 + lq * 16);
        }
        #pragma unroll
        for (int rt = 0; rt < 4; ++rt) {
            const int ar = rt * 16 + lr;
            const half8 ah = *(const half8*)((const char*)AsH + ar * 80 + lq * 16);
            const half8 al = *(const half8*)((const char*)AsL + ar * 80 + lq * 16);
            #pragma unroll
            for (int ct = 0; ct < 4; ++ct) {
                acc[rt][ct] = __builtin_amdgcn_mfma_f32_16x16x32_f16(ah, bhv[ct], acc[rt][ct], 0, 0, 0);
                acc[rt][ct] = __builtin_amdgcn_mfma_f32_16x16x32_f16(ah, blv[ct], acc[rt][ct], 0, 0, 0);
                acc[rt][ct] = __builtin_amdgcn_mfma_f32_16x16x32_f16(al, bhv[ct], acc[rt][ct], 0, 0, 0);
            }
        }
        __syncthreads();
    }

    _Float16* ph = (_Float16*)Eh;
    _Float16* pl = (_Float16*)El;
    const float sc = 1.0f / 1024.0f;
    #pragma unroll
    for (int rt = 0; rt < 4; ++rt) {
        #pragma unroll
        for (int r = 0; r < 4; ++r) {
            const int grr = m0 + rt * 16 + lq * 4 + r;
            if (grr >= Mtot) continue;
            #pragma unroll
            for (int ct = 0; ct < 4; ++ct) {
                const int gc = wc + ct * 16 + lr;
                const float vv = fmaxf(acc[rt][ct][r] * sc + bias[gc], 0.0f);
                const _Float16 hv = (_Float16)vv;
                ph[(size_t)grr * EDIM + gc] = hv;
                pl[(size_t)grr * EDIM + gc] = (_Float16)(vv - (float)hv);
            }
        }
    }
}

// ---------------------------------------------------------------------------
// Direct fp32 GEMM (NT, fused bias+relu) — fallback only (ws too small).
// ---------------------------------------------------------------------------
__global__ __launch_bounds__(256)
void k_embed_gemm(const float* __restrict__ S0, int n0,
                  const float* __restrict__ S1, int n1,
                  const float* __restrict__ S2,
                  const float* __restrict__ W, const float* __restrict__ bias,
                  float* __restrict__ C, int Mtot, int K) {
    __shared__ alignas(16) float As[16][68];
    __shared__ alignas(16) float Bs[16][68];
    const int tid  = threadIdx.x;
    const int tx   = tid & 15, ty = tid >> 4;
    const int m0   = blockIdx.x * 64, nc0 = blockIdx.y * 64;
    const int lrow = tid >> 2;
    const int lk4  = (tid & 3) << 2;

    const int gr = m0 + lrow;
    const float* srow = nullptr;
    if (gr < n0)            srow = S0 + (size_t)gr * K;
    else if (gr < n0 + n1)  srow = S1 + (size_t)(gr - n0) * K;
    else if (gr < Mtot)     srow = S2;
    const float* wrow = W + (size_t)(nc0 + lrow) * K;

    float acc[4][4] = {};
    for (int k0 = 0; k0 < K; k0 += 16) {
        float4 va = make_float4(0.f, 0.f, 0.f, 0.f);
        if (srow) va = *(const float4*)(srow + k0 + lk4);
        const float4 vb = *(const float4*)(wrow + k0 + lk4);
        As[lk4+0][lrow] = va.x; As[lk4+1][lrow] = va.y;
        As[lk4+2][lrow] = va.z; As[lk4+3][lrow] = va.w;
        Bs[lk4+0][lrow] = vb.x; Bs[lk4+1][lrow] = vb.y;
        Bs[lk4+2][lrow] = vb.z; Bs[lk4+3][lrow] = vb.w;
        __syncthreads();
        #pragma unroll
        for (int kk = 0; kk < 16; ++kk) {
            const float4 a4 = *(const float4*)&As[kk][ty << 2];
            const float4 b4 = *(const float4*)&Bs[kk][tx << 2];
            const float av[4] = {a4.x, a4.y, a4.z, a4.w};
            const float bv[4] = {b4.x, b4.y, b4.z, b4.w};
            #pragma unroll
            for (int i2 = 0; i2 < 4; ++i2)
                #pragma unroll
                for (int j2 = 0; j2 < 4; ++j2)
                    acc[i2][j2] = fmaf(av[i2], bv[j2], acc[i2][j2]);
        }
        __syncthreads();
    }
    #pragma unroll
    for (int i2 = 0; i2 < 4; ++i2) {
        const int grr = m0 + (ty << 2) + i2;
        if (grr >= Mtot) continue;
        #pragma unroll
        for (int j2 = 0; j2 < 4; ++j2) {
            const int gc = nc0 + (tx << 2) + j2;
            const float vv = acc[i2][j2] + bias[gc];
            C[(size_t)grr * EDIM + gc] = fmaxf(vv, 0.0f);
        }
    }
}

// ---------------------------------------------------------------------------
// Per-pair scaled edit-cost matrix via MFMA Gram; staging = plane copies,
// norms precomputed.
// ---------------------------------------------------------------------------
#define CSTR 36
__global__ __launch_bounds__(256)
void k_costs(const unsigned* __restrict__ Eh, const unsigned* __restrict__ El,
             const float* __restrict__ Norms,
             const int* __restrict__ len_s, const int* __restrict__ len_t,
             int Ns, int Nt, float* __restrict__ costs) {
    __shared__ alignas(16) unsigned Ah[34 * CSTR], Al[34 * CSTR];
    __shared__ alignas(16) unsigned Bh[34 * CSTR], Bl[34 * CSTR];
    __shared__ float dtile[LMAXP1 * LMAXP1];
    __shared__ float na[LMAXP1], nb[LMAXP1];
    __shared__ float red[256];
    __shared__ float s_scale;
    const int p = blockIdx.x, tid = threadIdx.x;
    const int n = len_s[p], m = len_t[p];
    int offs = 0, offt = 0;
    for (int j = 0; j < p; ++j) { offs += len_s[j]; offt += len_t[j]; }  // uniform
    const int veRow = Ns + Nt;
    const int tbase = Ns + offt;

    const int lane = tid & 63, wv = tid >> 6;
    const int lr = lane & 15, lq = lane >> 4;

    if (tid <= n)                       na[tid] = Norms[(tid < n) ? offs + tid : veRow];
    else if (tid >= 64 && tid - 64 <= m) nb[tid - 64] = Norms[(tid - 64 < m) ? tbase + tid - 64 : veRow];

    f32x4 g0 = {}, g1 = {}, g2 = {};
    const int t0 = wv, t1 = wv + 4, t2 = wv + 8;

    for (int k0 = 0; k0 < EDIM; k0 += 64) {
        for (int idx = tid; idx < 34 * 16; idx += 256) {
            const int r = idx >> 4, c4 = idx & 15;
            const int rowA = (r < n) ? offs + r : ((r == n) ? veRow : -1);
            const int rowB = (r < m) ? tbase + r : ((r == m) ? veRow : -1);
            uint2 vah = make_uint2(0,0), val = vah, vbh = vah, vbl = vah;
            if (rowA >= 0) {
                const size_t uo_ = (size_t)rowA * 128 + (k0 >> 1) + c4 * 2;
                vah = *(const uint2*)(Eh + uo_); val = *(const uint2*)(El + uo_);
            }
            if (rowB >= 0) {
                const size_t uo_ = (size_t)rowB * 128 + (k0 >> 1) + c4 * 2;
                vbh = *(const uint2*)(Eh + uo_); vbl = *(const uint2*)(El + uo_);
            }
            const int uo = r * CSTR + c4 * 2;
            *(uint2*)(Ah + uo) = vah; *(uint2*)(Al + uo) = val;
            *(uint2*)(Bh + uo) = vbh; *(uint2*)(Bl + uo) = vbl;
        }
        __syncthreads();

        #pragma unroll
        for (int kf = 0; kf < 2; ++kf) {
#define GRAM_TILE(T, G) { \
            const int tr_ = (T) / 3, tc_ = (T) % 3;                              \
            const int ar_ = tr_ * 16 + lr, br_ = tc_ * 16 + lr;                  \
            const half8 ah = *(const half8*)((const char*)Ah + ar_*144 + kf*64 + lq*16); \
            const half8 al = *(const half8*)((const char*)Al + ar_*144 + kf*64 + lq*16); \
            const half8 bh = *(const half8*)((const char*)Bh + br_*144 + kf*64 + lq*16); \
            const half8 bl = *(const half8*)((const char*)Bl + br_*144 + kf*64 + lq*16); \
            G = __builtin_amdgcn_mfma_f32_16x16x32_f16(ah, bh, G, 0, 0, 0);      \
            G = __builtin_amdgcn_mfma_f32_16x16x32_f16(ah, bl, G, 0, 0, 0);      \
            G = __builtin_amdgcn_mfma_f32_16x16x32_f16(al, bh, G, 0, 0, 0); }
            GRAM_TILE(t0, g0)
            GRAM_TILE(t1, g1)
            if (wv == 0) GRAM_TILE(t2, g2)
#undef GRAM_TILE
        }
        __syncthreads();
    }

#define DTILE_OUT(T, G) { \
    const int tr_ = (T) / 3, tc_ = (T) % 3;                                      \
    _Pragma("unroll")                                                            \
    for (int r = 0; r < 4; ++r) {                                                \
        const int i_ = tr_ * 16 + lq * 4 + r, j_ = tc_ * 16 + lr;                \
        if (i_ <= n && j_ <= m) {                                                \
            const float sq = fmaxf(na[i_] + nb[j_] - 2.0f * G[r], 0.0f);         \
            dtile[i_ * LMAXP1 + j_] = (sq > 0.0f) ? sqrtf(sq) : 0.0f;            \
        } } }
    DTILE_OUT(t0, g0)
    DTILE_OUT(t1, g1)
    if (wv == 0) DTILE_OUT(t2, g2)
#undef DTILE_OUT
    __syncthreads();

    float lsum = 0.f;
    const int m1 = m + 1;
    const int cells = (n + 1) * m1;
    for (int c = tid; c < cells; c += 256) {
        const int i = c / m1, j = c - i * m1;
        lsum += dtile[i * LMAXP1 + j];
    }
    red[tid] = lsum;
    __syncthreads();
    for (int s = 128; s > 0; s >>= 1) {
        if (tid < s) red[tid] += red[tid + s];
        __syncthreads();
    }
    if (tid == 0) s_scale = (float)(n * m) / red[0];
    __syncthreads();
    const float scale = s_scale;
    for (int idx = tid; idx < LMAXP1 * LMAXP1; idx += 256) {
        const int i = idx / LMAXP1, j = idx - i * LMAXP1;
        const float v = (i <= n && j <= m) ? dtile[i * LMAXP1 + j] * scale : 0.0f;
        costs[(size_t)p * (LMAXP1 * LMAXP1) + idx] = v;
    }
}

// ---------------------------------------------------------------------------
// LAP: SQUARE max(n,m)^2 solver (R20-proven machinery) on the COLUMN-SHIFTED
// matrix: M'[i][j] = min(sub,del+ins) - ins_j (real rows), M'[pad][j] = 0.
// Column-constant shift => identical optimal assignment set as R20 (decode
// reads ec, unchanged). Zero padding rows: (a) col-reduction v = min(..,0)
// automatically; (b) padding-vs-padding steals are TIES -> tie-guard path,
// no steal-thrash. Col-reduction/greedy + ARR + JV Dijkstra verbatim R20.
// ---------------------------------------------------------------------------
__device__ inline int rdlane_i(int v, int l) { return __builtin_amdgcn_readlane(v, l); }
__device__ inline float rdlane_f(float v, int l) {
    return __int_as_float(__builtin_amdgcn_readlane(__float_as_int(v), l));
}
__device__ inline unsigned wave_umin64(unsigned x) {
#define DPPMINU(ctrl) { unsigned t_ = (unsigned)__builtin_amdgcn_update_dpp(  \
        (int)x, (int)x, (ctrl), 0xf, 0xf, false);                             \
        x = (t_ < x) ? t_ : x; }
    DPPMINU(0xB1)
    DPPMINU(0x4E)
    DPPMINU(0x141)
    DPPMINU(0x140)
    DPPMINU(0x142)
    DPPMINU(0x143)
#undef DPPMINU
    return (unsigned)__builtin_amdgcn_readlane((int)x, 63);
}

__global__ __launch_bounds__(64)
void k_lap(const float* __restrict__ costs, const int* __restrict__ len_s,
           const int* __restrict__ len_t, float* __restrict__ aligns,
           float* __restrict__ geds) {
    __shared__ float ec[LMAXP1 * LMAXP1];
    __shared__ float Ms[33 * 64];
    const int p = blockIdx.x, lane = threadIdx.x;
    const int n = len_s[p], m = len_t[p];
    const float* cp = costs + (size_t)p * (LMAXP1 * LMAXP1);
    for (int idx = lane; idx < LMAXP1 * LMAXP1; idx += 64) ec[idx] = cp[idx];
    __syncthreads();

    const bool swp = (n > m);
    const int R  = swp ? n : m;
    const int S_ = swp ? m : n;
    const bool vec = (lane >= 1 && lane <= R);

    // ins cost of this column (insertion for !swp, deletion for swp)
    float insc = 0.0f;
    if (vec) insc = (!swp) ? ec[n * LMAXP1 + (lane - 1)]
                           : ec[(lane - 1) * LMAXP1 + m];

    // Column-shifted square matrix: padding rows exactly 0.
    for (int r = 1; r <= R; ++r) {
        float cv = FBIG;
        const int i0b = r - 1, j0b = lane - 1;
        if (vec) {
            if (i0b < S_) {
                if (!swp) cv = fminf(ec[i0b * LMAXP1 + j0b],
                                     ec[i0b * LMAXP1 + m] + insc) - insc;
                else      cv = fminf(ec[j0b * LMAXP1 + i0b],
                                     ec[n * LMAXP1 + i0b] + insc) - insc;
            } else {
                cv = 0.0f;
            }
        }
        Ms[(r << 6) + lane] = cv;
    }
    __syncthreads();

    // ---- column reduction + greedy ----
    float v_l = 0.0f;
    int amin_l = 0;
    if (vec) {
        float best = FBIG;
        for (int r = 1; r <= R; ++r) {
            const float c = Ms[(r << 6) + lane];
            if (c < best) { best = c; amin_l = r; }
        }
        v_l = best;
    }
    int p_l = 0;
    unsigned long long rowfree = ((1ull << R) - 1ull) << 1;
    for (int j = 1; j <= R; ++j) {
        const int ai = rdlane_i(amin_l, j);
        if ((rowfree >> ai) & 1ull) {
            if (lane == j) p_l = ai;
            rowfree &= ~(1ull << ai);
        }
    }

    // ---- augmenting row reduction (ARR) ----
    float ucol = 0.0f;
    {
        unsigned long long q = rowfree;
        int pops = 0;
        const int cap = 3 * R;
        while (q && pops < cap) {
            const int i = __ffsll(q) - 1;
            q &= ~(1ull << i);
            ++pops;
            const float rc = vec ? fmaxf(Ms[(i << 6) + lane] - v_l, 0.0f) : FBIG;
            const unsigned key = (__float_as_uint(rc) & ~63u) | (unsigned)lane;
            const unsigned k1 = wave_umin64(key);
            int j1 = (int)(k1 & 63u);
            const float min1 = rdlane_f(rc, j1);
            const unsigned key2 = (lane == j1) ? 0xFFFFFFFFu : key;
            const unsigned k2 = wave_umin64(key2);
            const float min2 = rdlane_f(rc, (int)(k2 & 63u));
            int owner = rdlane_i(p_l, j1);
            const bool strict = (min1 < min2);
            if (!strict) {
                const unsigned long long ball =
                    __ballot(vec && (rc == min1) && (p_l == 0));
                if (ball == 0ull) continue;
                j1 = __ffsll(ball) - 1;
                j1 = __builtin_amdgcn_readfirstlane(j1);
                owner = 0;
            }
            if (lane == j1) {
                p_l = i; ucol = min2;
                if (strict) v_l -= (min2 - min1);
            }
            rowfree &= ~(1ull << i);
            if (owner != 0) { rowfree |= (1ull << owner); q |= (1ull << owner); }
        }
    }

    // ---- JV Dijkstra for remaining free rows ----
    float minv_l = FBIG;
    int way_l = 0;

    for (int i = 1; i <= R; ++i) {
        if (!((rowfree >> i) & 1ull)) continue;
        if (lane == 0) { p_l = i; ucol = 0.0f; }
        minv_l = FBIG;
        int used_l = 0;
        int j0 = 0, i0 = i;
        float u_i0 = 0.0f;
        while (true) {
            if (lane == j0) used_l = 1;
            const float cur = Ms[(i0 << 6) + lane] - u_i0 - v_l;
            const bool unused = vec && !used_l;
            if (unused && cur < minv_l) { minv_l = cur; way_l = j0; }
            const float mval = unused ? fmaxf(minv_l, 0.0f) : FBIG;
            const unsigned key = (__float_as_uint(mval) & ~63u) | (unsigned)lane;
            const unsigned kmin = wave_umin64(key);
            const int j1 = (int)(kmin & 63u);
            const float delta = rdlane_f(minv_l, j1);
            if (used_l) { ucol += delta; v_l -= delta; }
            if (unused) minv_l -= delta;
            j0 = j1;
            i0 = rdlane_i(p_l, j1);
            u_i0 = rdlane_f(ucol, j1);
            if (i0 == 0) break;
        }
        int jj = j0;
        while (jj != 0) {
            const int   j1a = rdlane_i(way_l, jj);
            const int   pn  = rdlane_i(p_l, j1a);
            const float un  = rdlane_f(ucol, j1a);
            if (lane == jj) { p_l = pn; ucol = un; }
            jj = j1a;
        }
    }

    // ---- decode (reads ec; identical to R20) ----
    float* ap = aligns + (size_t)p * (LMAXP1 * LMAXP1);
    for (int idx = lane; idx < LMAXP1 * LMAXP1; idx += 64) ap[idx] = 0.0f;
    __syncthreads();
    float gedv = 0.0f;
    if (vec) {
        const int i0b = p_l - 1;
        const int j0b = lane - 1;
        if (!swp) {
            if (i0b < S_) {
                const float sub = ec[i0b * LMAXP1 + j0b];
                const float alt = ec[i0b * LMAXP1 + m] + ec[n * LMAXP1 + j0b];
                if (sub <= alt) { ap[i0b * LMAXP1 + j0b] = 1.0f; gedv = sub; }
                else { ap[i0b * LMAXP1 + m] = 1.0f;
                       ap[n * LMAXP1 + j0b] = 1.0f;
                       gedv = alt; }
            } else {
                ap[n * LMAXP1 + j0b] = 1.0f;
                gedv = ec[n * LMAXP1 + j0b];
            }
        } else {
            if (i0b < S_) {
                const float sub = ec[j0b * LMAXP1 + i0b];
                const float alt = ec[n * LMAXP1 + i0b] + ec[j0b * LMAXP1 + m];
                if (sub <= alt) { ap[j0b * LMAXP1 + i0b] = 1.0f; gedv = sub; }
                else { ap[n * LMAXP1 + i0b] = 1.0f;
                       ap[j0b * LMAXP1 + m] = 1.0f;
                       gedv = alt; }
            } else {
                ap[j0b * LMAXP1 + m] = 1.0f;
                gedv = ec[j0b * LMAXP1 + m];
            }
        }
    }
    #pragma unroll
    for (int off = 32; off > 0; off >>= 1) gedv += __shfl_xor(gedv, off);
    if (lane == 0) geds[p] = gedv / (float)(n + m);
}

// ---------------------------------------------------------------------------
extern "C" void kernel_launch(void* const* d_in, const int* in_sizes, int n_in,
                              void* d_out, int out_size, void* d_ws, size_t ws_size,
                              hipStream_t stream) {
    const float* x_s = (const float*)d_in[0];
    const float* x_t = (const float*)d_in[1];
    const float* W1  = (const float*)d_in[2];
    const float* b1  = (const float*)d_in[3];
    const float* W2  = (const float*)d_in[4];
    const float* b2  = (const float*)d_in[5];
    const float* ve  = (const float*)d_in[6];
    const int* len_s = (const int*)d_in[7];
    const int* len_t = (const int*)d_in[8];
    const int P    = in_sizes[7];
    const int Ns   = in_sizes[0] / 2048;
    const int Nt   = in_sizes[1] / 2048;
    const int Mtot = Ns + Nt + 1;
    const size_t MN  = (size_t)Mtot * EDIM;          // even

    float* out_aligns = (float*)d_out;
    float* out_costs  = out_aligns + (size_t)P * LMAXP1 * LMAXP1;
    float* out_geds   = out_costs  + (size_t)P * LMAXP1 * LMAXP1;

    const dim3 b256(256);
    const int gx64  = (Mtot + 63) / 64;
    const int gx128 = (Mtot + 127) / 128;
    const int gnorm = (Mtot + 3) / 4;

    const size_t fixed = MN + 10240 + 2 * 262144 + 2 * 32768;
    int S = 0;
    if (ws_size >= (4 * MN + fixed) * sizeof(float)) S = 4;
    else if (ws_size >= (2 * MN + fixed) * sizeof(float)) S = 2;

    if (S > 0) {
        float* Part = (float*)d_ws;
        unsigned* Eh  = (unsigned*)Part;              // MN/2 uints (alias)
        unsigned* El  = Eh + MN / 2;
        unsigned* Hh  = (unsigned*)(Part + (size_t)S * MN);
        unsigned* Hl  = Hh + MN / 2;
        float* Norms  = (float*)(Hl + MN / 2);
        unsigned* W1h = (unsigned*)(Norms + 10240);
        unsigned* W1l = W1h + 262144;
        unsigned* W2h = W1l + 262144;
        unsigned* W2l = W2h + 32768;

        k_convw<<<dim3(1024), b256, 0, stream>>>(W1, W1h, W1l, 262144, 1024.0f);
        k_convw<<<dim3(128),  b256, 0, stream>>>(W2, W2h, W2l, 32768, 1024.0f);

        k_gemm_splitk<<<dim3(gx128, 2, S), b256, 0, stream>>>(
            x_s, Ns, x_t, Nt, ve, W1h, W1l, Part, Mtot, 2048, 2048 / S);

        const size_t MN4 = MN / 4;
        const int rblocks = (int)((MN4 + 255) / 256) < 2048
                          ? (int)((MN4 + 255) / 256) : 2048;
        k_reduce_bias_relu<<<dim3(rblocks), b256, 0, stream>>>(Part, b1, Hh, Hl, S, MN4);

        k_gemm_f16<<<dim3(gx64), b256, 0, stream>>>(Hh, Hl, W2h, W2l, b2, Eh, El, Mtot, 256);
        k_norms<<<dim3(gnorm), b256, 0, stream>>>(Eh, El, Norms, Mtot);

        k_costs<<<dim3(P), b256, 0, stream>>>(Eh, El, Norms, len_s, len_t, Ns, Nt, out_costs);
        k_lap<<<dim3(P), dim3(64), 0, stream>>>(out_costs, len_s, len_t, out_aligns, out_geds);
    } else {
        float* H   = (float*)d_ws;
        float* Emb = H + MN;
        unsigned* Eh = (unsigned*)(Emb + MN);
        unsigned* El = Eh + MN / 2;
        float* Norms = (float*)(El + MN / 2);
        k_embed_gemm<<<dim3(gx64, 4), b256, 0, stream>>>(
            x_s, Ns, x_t, Nt, ve, W1, b1, H, Mtot, 2048);
        k_embed_gemm<<<dim3(gx64, 4), b256, 0, stream>>>(
            H, Mtot, nullptr, 0, nullptr, W2, b2, Emb, Mtot, 256);
        k_convw<<<dim3(1024), b256, 0, stream>>>(Emb, Eh, El, (int)(MN / 2), 1.0f);
        k_norms<<<dim3(gnorm), b256, 0, stream>>>(Eh, El, Norms, Mtot);
        k_costs<<<dim3(P), b256, 0, stream>>>(Eh, El, Norms, len_s, len_t, Ns, Nt, out_costs);
        k_lap<<<dim3(P), dim3(64), 0, stream>>>(out_costs, len_s, len_t, out_aligns, out_geds);
    }
}